// Round 8
// baseline (47522.992 us; speedup 1.0000x reference)
//
#include <hip/hip_runtime.h>

// Seq2Seq forward. R8: decoder restructured — 32 blocks, per-batch fused
// attention pipeline in-block (LDS intermediates), TWO grid barriers/step
// (encoder-proven 32x32 flag structure) instead of R7's 7 barriers over 256
// blocks whose 65k device-scope flag polls cost ~45us each (profile: dec 20ms
// at 2.6% VALUBusy). Weights for the per-batch phase pre-packed to bf16.

#define DI __device__ __forceinline__

constexpr int BATCH = 32;
constexpr int TS = 1024;
constexpr int TG = 64;
constexpr int HID = 512;
constexpr int GD = 2048;
constexpr int EDIM = 256;
constexpr int SPECIAL = 4;
constexpr size_t OFF_H = (size_t)BATCH * TG * EDIM;
constexpr size_t OFF_C = OFF_H + (size_t)BATCH * TG * HID;
constexpr int FLAG_STRIDE = 16;   // dwords (64B) per flag

typedef __attribute__((ext_vector_type(8))) short bf16x8;
typedef __attribute__((ext_vector_type(4))) float f32x4;

DI float b2f(unsigned short u) {
  union { unsigned int i; float f; } v; v.i = ((unsigned int)u) << 16; return v.f;
}
DI unsigned short f2b(float f) {
  union { float f; unsigned int i; } v; v.f = f;
  unsigned int r = v.i + 0x7fffu + ((v.i >> 16) & 1u);
  return (unsigned short)(r >> 16);
}
DI float sigm(float x) { return 1.0f / (1.0f + expf(-x)); }
DI float ldf(const void* p, size_t i, int f32f) {
  return f32f ? ((const float*)p)[i] : b2f(((const unsigned short*)p)[i]);
}
DI void stf(void* p, size_t i, float v, int f32f) {
  if (f32f) ((float*)p)[i] = v; else ((unsigned short*)p)[i] = f2b(v);
}
DI unsigned int ald(const unsigned int* p) {
  return __hip_atomic_load(p, __ATOMIC_RELAXED, __HIP_MEMORY_SCOPE_AGENT);
}
DI void ast(unsigned int* p, unsigned int v) {
  __hip_atomic_store(p, v, __ATOMIC_RELAXED, __HIP_MEMORY_SCOPE_AGENT);
}

__global__ void detect_k(const void* art, int* flag) {
  int tid = threadIdx.x;
  float x = ((const float*)art)[tid + 1024];
  float a = fabsf(x);
  int sane = (x == 0.0f) || (a > 1e-8f && a < 1e4f);
  unsigned long long m = __ballot(sane);
  __shared__ int cnt[4];
  if ((tid & 63) == 0) cnt[tid >> 6] = __popcll(m);
  __syncthreads();
  if (tid == 0) flag[0] = (cnt[0] + cnt[1] + cnt[2] + cnt[3] > 128) ? 1 : 0;
}

__global__ void fill_sig_k(unsigned short* o, int n) {
  int g = blockIdx.x * 256 + threadIdx.x;
  if (g < n) o[g] = 0x42F6;
}

__global__ void pack_gate_k(const void* __restrict__ W,
                            unsigned short* __restrict__ pk, const int* dtf) {
  int f32f = dtf[0];
  int g = blockIdx.x * 256 + threadIdx.x;
  if (g >= (GD * HID) / 8) return;
  int lane = g & 63;
  int kk = (g >> 6) & 15;
  int tile = g >> 10;
  int p = tile * 16 + (lane & 15);
  int nloc = p & 63, blk = p >> 6;
  int orow = (nloc >> 4) * HID + blk * 16 + (nloc & 15);
  int k = kk * 32 + (lane >> 4) * 8;
  unsigned short tmp[8];
#pragma unroll
  for (int j = 0; j < 8; ++j) tmp[j] = f2b(ldf(W, (size_t)orow * HID + k + j, f32f));
  *(uint4*)(pk + (size_t)g * 8) = *(uint4*)tmp;
}

__global__ void pack_wm_k(const void* __restrict__ wm,
                          unsigned short* __restrict__ pk, const int* dtf) {
  int f32f = dtf[0];
  int g = blockIdx.x * 256 + threadIdx.x;
  if (g >= 32 * 32 * 64) return;
  int lane = g & 63;
  int kk = (g >> 6) & 31;
  int nt = g >> 11;
  int col = nt * 16 + (lane & 15);
  int kb = kk * 32 + (lane >> 4) * 8;
  unsigned short tmp[8];
#pragma unroll
  for (int j = 0; j < 8; ++j) tmp[j] = f2b(ldf(wm, (size_t)(kb + j) * HID + col, f32f));
  *(uint4*)(pk + (size_t)g * 8) = *(uint4*)tmp;
}

// flat external -> bf16 copy (for wq/W1/b1/W2)
__global__ void pack_bf16_k(const void* __restrict__ src,
                            unsigned short* __restrict__ dst, int n, const int* dtf) {
  int f32f = dtf[0];
  int g = blockIdx.x * 256 + threadIdx.x;
  if (g < n) dst[g] = f2b(ldf(src, g, f32f));
}

// ---------------------------------------------------------------------------
// Persistent bidirectional encoder (unchanged — proven).
// ---------------------------------------------------------------------------
__global__ __launch_bounds__(256, 1) void enc_all_k(
    const void* __restrict__ article,
    unsigned short* __restrict__ outF, unsigned short* __restrict__ outB,
    const unsigned short* __restrict__ hIF, const unsigned short* __restrict__ hIB,
    float* __restrict__ cF, float* __restrict__ cB,
    const unsigned short* __restrict__ pkXF, const unsigned short* __restrict__ pkHF,
    const unsigned short* __restrict__ pkXB, const unsigned short* __restrict__ pkHB,
    const void* __restrict__ bF, const void* __restrict__ bB,
    int* __restrict__ bar, const int* dtf) {
  const int f32f = dtf[0];
  const int blk = blockIdx.x;
  const int dir = blk >> 5;
  const int blk16 = blk & 31;
  const int tid = threadIdx.x;
  const int lane = tid & 63;
  const int wv = tid >> 6;
  const int tile = blk16 * 4 + wv;

  __shared__ unsigned short lstage[BATCH * HID];
  __shared__ float gbuf[BATCH * 68];

  const unsigned short* pkX = dir ? pkXB : pkXF;
  const unsigned short* pkH = dir ? pkHB : pkHF;
  const void* bias = dir ? bB : bF;
  unsigned short* out = dir ? outB : outF;
  const unsigned short* hI = dir ? hIB : hIF;
  float* cg = dir ? cB : cF;
  int* flp = bar + dir * 32 * FLAG_STRIDE;

  bf16x8 wx[16], wh[16];
  {
    const unsigned short* px = pkX + ((size_t)tile * 16 * 64 + lane) * 8;
    const unsigned short* ph = pkH + ((size_t)tile * 16 * 64 + lane) * 8;
#pragma unroll
    for (int kk = 0; kk < 16; ++kk) {
      wx[kk] = *(const bf16x8*)(px + (size_t)kk * 64 * 8);
      wh[kk] = *(const bf16x8*)(ph + (size_t)kk * 64 * 8);
    }
  }
  const int gb = tid >> 3;
  const int gj = (tid & 7) * 2;
  float c0 = cg[gb * HID + blk16 * 16 + gj];
  float c1 = cg[gb * HID + blk16 * 16 + gj + 1];

  const int r0 = lane & 15;
  const int r1 = 16 + r0;
  const int kbb = (lane >> 4) * 8;
  const int nloc = wv * 16 + (lane & 15);
  const int orow = (nloc >> 4) * HID + blk16 * 16 + (nloc & 15);
  const float bv = ldf(bias, orow, f32f);

  for (int t = 0; t < TS; ++t) {
    const int tsrc = dir ? (TS - 1 - t) : t;
#pragma unroll
    for (int it = 0; it < 8; ++it) {
      int ci = it * 256 + tid;
      int row = ci >> 6;
      int k8 = (ci & 63) << 3;
      unsigned off = (unsigned)(row * 1024 + ((k8 * 2) ^ ((row & 7) << 4)));
      if (f32f) {
        const float* s = (const float*)article + (size_t)tsrc * BATCH * HID +
                         (size_t)row * HID + k8;
        float4 u0 = *(const float4*)s;
        float4 u1 = *(const float4*)(s + 4);
        unsigned short tmp[8] = {f2b(u0.x), f2b(u0.y), f2b(u0.z), f2b(u0.w),
                                 f2b(u1.x), f2b(u1.y), f2b(u1.z), f2b(u1.w)};
        *(uint4*)((char*)lstage + off) = *(uint4*)tmp;
      } else {
        const unsigned short* s = (const unsigned short*)article +
                                  (size_t)tsrc * BATCH * HID + (size_t)row * HID + k8;
        *(uint4*)((char*)lstage + off) = *(const uint4*)s;
      }
    }
    __syncthreads();
    unsigned int* hu = (t == 0)
        ? (unsigned int*)hI
        : (unsigned int*)(out + (size_t)(tsrc + (dir ? 1 : -1)) * BATCH * HID);
    unsigned int hreg[32];
#pragma unroll
    for (int it = 0; it < 32; ++it) hreg[it] = ald(hu + it * 256 + tid);
    f32x4 acc0 = {0.f, 0.f, 0.f, 0.f};
    f32x4 acc1 = {0.f, 0.f, 0.f, 0.f};
#pragma unroll
    for (int kk = 0; kk < 16; ++kk) {
      unsigned o0 = (unsigned)(r0 * 1024 + (((kk * 32 + kbb) * 2) ^ ((r0 & 7) << 4)));
      unsigned o1 = (unsigned)(r1 * 1024 + (((kk * 32 + kbb) * 2) ^ ((r0 & 7) << 4)));
      bf16x8 a0 = *(const bf16x8*)((const char*)lstage + o0);
      bf16x8 a1 = *(const bf16x8*)((const char*)lstage + o1);
      acc0 = __builtin_amdgcn_mfma_f32_16x16x32_bf16(a0, wx[kk], acc0, 0, 0, 0);
      acc1 = __builtin_amdgcn_mfma_f32_16x16x32_bf16(a1, wx[kk], acc1, 0, 0, 0);
    }
    __syncthreads();
#pragma unroll
    for (int it = 0; it < 32; ++it) {
      int dw = it * 256 + tid;
      int row = dw >> 8;
      unsigned lb = (unsigned)(row * 1024 +
                               (((dw & 252) << 2) ^ ((row & 7) << 4)) +
                               ((dw & 3) << 2));
      *(unsigned int*)((char*)lstage + lb) = hreg[it];
    }
    __syncthreads();
#pragma unroll
    for (int kk = 0; kk < 16; ++kk) {
      unsigned o0 = (unsigned)(r0 * 1024 + (((kk * 32 + kbb) * 2) ^ ((r0 & 7) << 4)));
      unsigned o1 = (unsigned)(r1 * 1024 + (((kk * 32 + kbb) * 2) ^ ((r0 & 7) << 4)));
      bf16x8 a0 = *(const bf16x8*)((const char*)lstage + o0);
      bf16x8 a1 = *(const bf16x8*)((const char*)lstage + o1);
      acc0 = __builtin_amdgcn_mfma_f32_16x16x32_bf16(a0, wh[kk], acc0, 0, 0, 0);
      acc1 = __builtin_amdgcn_mfma_f32_16x16x32_bf16(a1, wh[kk], acc1, 0, 0, 0);
    }
#pragma unroll
    for (int r = 0; r < 4; ++r) {
      int brow = (lane >> 4) * 4 + r;
      gbuf[brow * 68 + nloc] = acc0[r] + bv;
      gbuf[(16 + brow) * 68 + nloc] = acc1[r] + bv;
    }
    __syncthreads();
    {
      float gi0 = gbuf[gb * 68 + gj],      gf0 = gbuf[gb * 68 + 16 + gj];
      float gg0 = gbuf[gb * 68 + 32 + gj], go0 = gbuf[gb * 68 + 48 + gj];
      float gi1 = gbuf[gb * 68 + gj + 1],      gf1 = gbuf[gb * 68 + 16 + gj + 1];
      float gg1 = gbuf[gb * 68 + 32 + gj + 1], go1 = gbuf[gb * 68 + 48 + gj + 1];
      float cn0 = sigm(gf0) * c0 + sigm(gi0) * tanhf(gg0); c0 = cn0;
      float cn1 = sigm(gf1) * c1 + sigm(gi1) * tanhf(gg1); c1 = cn1;
      unsigned int hv = (unsigned int)f2b(sigm(go0) * tanhf(cn0)) |
                        ((unsigned int)f2b(sigm(go1) * tanhf(cn1)) << 16);
      ast((unsigned int*)out + (size_t)tsrc * (BATCH * HID / 2) +
              gb * (HID / 2) + blk16 * 8 + (tid & 7), hv);
    }
    if (t + 1 < TS) {
      __syncthreads();
      if (wv == 0) {
        const int target = t + 1;
        if (lane == 0)
          __hip_atomic_store(flp + blk16 * FLAG_STRIDE, target,
                             __ATOMIC_RELAXED, __HIP_MEMORY_SCOPE_AGENT);
        for (;;) {
          int v = (lane < 32)
              ? __hip_atomic_load(flp + lane * FLAG_STRIDE, __ATOMIC_RELAXED,
                                  __HIP_MEMORY_SCOPE_AGENT)
              : 0x7fffffff;
          if (__all(v >= target)) break;
          __builtin_amdgcn_s_sleep(2);
        }
      }
      __syncthreads();
    }
  }
  cg[gb * HID + blk16 * 16 + gj] = c0;
  cg[gb * HID + blk16 * 16 + gj + 1] = c1;
}

// ---------------------------------------------------------------------------
// Persistent fused decoder, R8: 32 blocks, 2 grid barriers per step.
// Phase A: LSTM cell (block = 16-hidden-unit slice, MFMA over batch).
// Phase B: block b = batch b's full attention+projection pipeline, in-block.
// ---------------------------------------------------------------------------
__global__ __launch_bounds__(256, 1) void dec_all_k(
    unsigned short* __restrict__ xdec,
    unsigned short* __restrict__ hd0, unsigned short* __restrict__ hd1,
    const float* __restrict__ cdec,
    const unsigned short* __restrict__ pkX, const unsigned short* __restrict__ pkH,
    const void* __restrict__ dbias,
    const unsigned short* __restrict__ att,
    const unsigned short* __restrict__ wqp,   // bf16 [512][512]
    const unsigned short* __restrict__ W1p,   // bf16 [1024][512]
    const unsigned short* __restrict__ b1p,   // bf16 [512]
    const unsigned short* __restrict__ W2p,   // bf16 [512][256]
    const void* __restrict__ emb, const int* __restrict__ lens,
    void* __restrict__ dout,
    int* __restrict__ flags, const int* dtf) {
  const int f32f = dtf[0];
  const int blk = blockIdx.x;       // 0..31
  const int tid = threadIdx.x;
  const int lane = tid & 63;
  const int wv = tid >> 6;
  __shared__ __align__(16) char smem[49152];

  // phase-A constants
  const int gb = tid >> 3;
  const int gj = (tid & 7) * 2;
  const int r0 = lane & 15;
  const int r1 = 16 + r0;
  const int kbb = (lane >> 4) * 8;
  const int nloc = wv * 16 + (lane & 15);
  float c0 = cdec[gb * HID + blk * 16 + gj];
  float c1 = cdec[gb * HID + blk * 16 + gj + 1];
  const int orow = (nloc >> 4) * HID + blk * 16 + (nloc & 15);
  const float bv = ldf(dbias, orow, f32f);

  int ep = 0;
  auto gbar = [&]() {
    __syncthreads();   // vmcnt(0) drain: agent stores globally complete
    ++ep;
    if (wv == 0) {
      if (lane == 0)
        __hip_atomic_store(flags + blk * FLAG_STRIDE, ep, __ATOMIC_RELAXED,
                           __HIP_MEMORY_SCOPE_AGENT);
      for (;;) {
        int v = (lane < 32)
            ? __hip_atomic_load(flags + lane * FLAG_STRIDE, __ATOMIC_RELAXED,
                                __HIP_MEMORY_SCOPE_AGENT)
            : 0x7fffffff;
        if (__all(v >= ep)) break;
        __builtin_amdgcn_s_sleep(2);
      }
    }
    __syncthreads();
  };

  for (int i = 0; i < TG; ++i) {
    unsigned short* hin = (i & 1) ? hd1 : hd0;
    unsigned short* hout = (i & 1) ? hd0 : hd1;

    // ================= Phase A: LSTM cell =================
    {
      unsigned short* lstage = (unsigned short*)smem;      // 32 KB swizzled
      float* gbuf = (float*)(smem + 32768);                // 8.5 KB
      const unsigned int* xu = (const unsigned int*)xdec;
      unsigned int xreg[32];
#pragma unroll
      for (int it = 0; it < 32; ++it) xreg[it] = ald(xu + it * 256 + tid);
#pragma unroll
      for (int it = 0; it < 32; ++it) {
        int dw = it * 256 + tid;
        int row = dw >> 8;
        unsigned lb = (unsigned)(row * 1024 +
                                 (((dw & 252) << 2) ^ ((row & 7) << 4)) +
                                 ((dw & 3) << 2));
        *(unsigned int*)((char*)lstage + lb) = xreg[it];
      }
      __syncthreads();
      const unsigned int* hu = (const unsigned int*)hin;
      unsigned int hreg[32];
#pragma unroll
      for (int it = 0; it < 32; ++it) hreg[it] = ald(hu + it * 256 + tid);
      const int tile = blk * 4 + wv;
      const unsigned short* pwx = pkX + (size_t)tile * 16 * 64 * 8;
      const unsigned short* pwh = pkH + (size_t)tile * 16 * 64 * 8;
      f32x4 acc0 = {0.f, 0.f, 0.f, 0.f};
      f32x4 acc1 = {0.f, 0.f, 0.f, 0.f};
#pragma unroll
      for (int kk = 0; kk < 16; ++kk) {
        unsigned o0 = (unsigned)(r0 * 1024 + (((kk * 32 + kbb) * 2) ^ ((r0 & 7) << 4)));
        unsigned o1 = (unsigned)(r1 * 1024 + (((kk * 32 + kbb) * 2) ^ ((r0 & 7) << 4)));
        bf16x8 a0 = *(const bf16x8*)((const char*)lstage + o0);
        bf16x8 a1 = *(const bf16x8*)((const char*)lstage + o1);
        bf16x8 bb = *(const bf16x8*)(pwx + (size_t)(kk * 64 + lane) * 8);
        acc0 = __builtin_amdgcn_mfma_f32_16x16x32_bf16(a0, bb, acc0, 0, 0, 0);
        acc1 = __builtin_amdgcn_mfma_f32_16x16x32_bf16(a1, bb, acc1, 0, 0, 0);
      }
      __syncthreads();
#pragma unroll
      for (int it = 0; it < 32; ++it) {
        int dw = it * 256 + tid;
        int row = dw >> 8;
        unsigned lb = (unsigned)(row * 1024 +
                                 (((dw & 252) << 2) ^ ((row & 7) << 4)) +
                                 ((dw & 3) << 2));
        *(unsigned int*)((char*)lstage + lb) = hreg[it];
      }
      __syncthreads();
#pragma unroll
      for (int kk = 0; kk < 16; ++kk) {
        unsigned o0 = (unsigned)(r0 * 1024 + (((kk * 32 + kbb) * 2) ^ ((r0 & 7) << 4)));
        unsigned o1 = (unsigned)(r1 * 1024 + (((kk * 32 + kbb) * 2) ^ ((r0 & 7) << 4)));
        bf16x8 a0 = *(const bf16x8*)((const char*)lstage + o0);
        bf16x8 a1 = *(const bf16x8*)((const char*)lstage + o1);
        bf16x8 bb = *(const bf16x8*)(pwh + (size_t)(kk * 64 + lane) * 8);
        acc0 = __builtin_amdgcn_mfma_f32_16x16x32_bf16(a0, bb, acc0, 0, 0, 0);
        acc1 = __builtin_amdgcn_mfma_f32_16x16x32_bf16(a1, bb, acc1, 0, 0, 0);
      }
#pragma unroll
      for (int r = 0; r < 4; ++r) {
        int brow = (lane >> 4) * 4 + r;
        gbuf[brow * 68 + nloc] = acc0[r] + bv;
        gbuf[(16 + brow) * 68 + nloc] = acc1[r] + bv;
      }
      __syncthreads();
      {
        float gi0 = gbuf[gb * 68 + gj],      gf0 = gbuf[gb * 68 + 16 + gj];
        float gg0 = gbuf[gb * 68 + 32 + gj], go0 = gbuf[gb * 68 + 48 + gj];
        float gi1 = gbuf[gb * 68 + gj + 1],      gf1 = gbuf[gb * 68 + 16 + gj + 1];
        float gg1 = gbuf[gb * 68 + 32 + gj + 1], go1 = gbuf[gb * 68 + 48 + gj + 1];
        float cn0 = sigm(gf0) * c0 + sigm(gi0) * tanhf(gg0); c0 = cn0;
        float cn1 = sigm(gf1) * c1 + sigm(gi1) * tanhf(gg1); c1 = cn1;
        float hn0 = sigm(go0) * tanhf(cn0);
        float hn1 = sigm(go1) * tanhf(cn1);
        ast((unsigned int*)hout + gb * (HID / 2) + blk * 8 + (tid & 7),
            (unsigned int)f2b(hn0) | ((unsigned int)f2b(hn1) << 16));
        size_t e0 = ((size_t)gb * TG + i) * HID + blk * 16 + gj;
        stf(dout, OFF_H + e0, hn0, f32f);
        stf(dout, OFF_H + e0 + 1, hn1, f32f);
        stf(dout, OFF_C + e0, cn0, f32f);
        stf(dout, OFF_C + e0 + 1, cn1, f32f);
      }
    }
    gbar();   // h complete

    // ================= Phase B: per-batch pipeline (block = batch b) =======
    {
      const int b = blk;
      const int len = lens[b];
      unsigned short* lhB = (unsigned short*)smem;            // [512] bf16
      float* qf   = (float*)(smem + 1024);                    // [512] f32
      float* sc   = (float*)(smem + 4096);                    // [1024] f32
      float* red  = (float*)(smem + 8192);                    // [256] f32
      float* cred = (float*)(smem + 12288);                   // [4][512] f32
      float* ctxf = (float*)(smem + 20480);                   // [512] f32
      unsigned short* zl = (unsigned short*)(smem + 22528);   // [512] bf16

      // h[b] -> LDS
      ((unsigned int*)lhB)[tid] = ald((const unsigned int*)hout + b * 256 + tid);
      __syncthreads();

      // query[n0,n1], n0=2tid: q = h[b] @ wq   (wq bf16-packed, dword pairs)
      {
        float a0 = 0.f, a1 = 0.f;
        const unsigned int* wqu = (const unsigned int*)wqp;
        for (int k = 0; k < HID; ++k) {
          float hv = b2f(lhB[k]);
          unsigned int wp = wqu[k * 256 + tid];
          a0 += hv * b2f((unsigned short)wp);
          a1 += hv * b2f((unsigned short)(wp >> 16));
        }
        qf[2 * tid] = a0;
        qf[2 * tid + 1] = a1;
      }
      __syncthreads();

      // score: wave wv covers t in [wv*256, wv*256+256); row-per-wave reduce
      {
        float qv[8];
#pragma unroll
        for (int j = 0; j < 8; ++j) qv[j] = qf[lane * 8 + j];
        for (int tt = 0; tt < 256; ++tt) {
          int t = wv * 256 + tt;
          bf16x8 a8 = *(const bf16x8*)(att + ((size_t)b * TS + t) * HID + lane * 8);
          float s = 0.f;
#pragma unroll
          for (int e = 0; e < 8; ++e)
            s += qv[e] * b2f(((const unsigned short*)&a8)[e]);
          for (int off2 = 32; off2; off2 >>= 1) s += __shfl_xor(s, off2, 64);
          if (lane == 0) sc[t] = s;
        }
      }
      __syncthreads();

      // softmax over sc[0..len) in place (sc -> probs)
      {
        float sv[4], mx = -1e30f;
#pragma unroll
        for (int q = 0; q < 4; ++q) {
          int t = q * 256 + tid;
          float v = (t < len) ? sc[t] : -1e30f;
          sv[q] = v; mx = fmaxf(mx, v);
        }
        red[tid] = mx; __syncthreads();
        for (int st = 128; st; st >>= 1) { if (tid < st) red[tid] = fmaxf(red[tid], red[tid + st]); __syncthreads(); }
        mx = red[0]; __syncthreads();
        float e[4], sum = 0.f;
#pragma unroll
        for (int q = 0; q < 4; ++q) { e[q] = (sv[q] > -1e29f) ? expf(sv[q] - mx) : 0.f; sum += e[q]; }
        red[tid] = sum; __syncthreads();
        for (int st = 128; st; st >>= 1) { if (tid < st) red[tid] += red[tid + st]; __syncthreads(); }
        sum = red[0]; __syncthreads();
#pragma unroll
        for (int q = 0; q < 4; ++q) sc[q * 256 + tid] = e[q] / sum;
      }
      __syncthreads();

      // context: wave wv sums t = wv::4; lane owns cols lane*8..+7
      {
        float ca[8] = {0.f, 0.f, 0.f, 0.f, 0.f, 0.f, 0.f, 0.f};
        for (int t = wv; t < TS; t += 4) {
          float p = sc[t];
          bf16x8 a8 = *(const bf16x8*)(att + ((size_t)b * TS + t) * HID + lane * 8);
#pragma unroll
          for (int e = 0; e < 8; ++e)
            ca[e] += p * b2f(((const unsigned short*)&a8)[e]);
        }
#pragma unroll
        for (int e = 0; e < 8; ++e) cred[wv * 512 + lane * 8 + e] = ca[e];
      }
      __syncthreads();
      ctxf[tid] = cred[tid] + cred[512 + tid] + cred[1024 + tid] + cred[1536 + tid];
      ctxf[256 + tid] = cred[256 + tid] + cred[768 + tid] + cred[1280 + tid] + cred[1792 + tid];
      __syncthreads();

      // z[n0,n1] = tanh(b1 + h@W1[:512] + ctx@W1[512:])
      {
        float a0 = b2f(b1p[2 * tid]);
        float a1 = b2f(b1p[2 * tid + 1]);
        const unsigned int* w1u = (const unsigned int*)W1p;
        for (int k = 0; k < HID; ++k) {
          float hv = b2f(lhB[k]);
          unsigned int wp = w1u[k * 256 + tid];
          a0 += hv * b2f((unsigned short)wp);
          a1 += hv * b2f((unsigned short)(wp >> 16));
        }
        for (int k = 0; k < HID; ++k) {
          float cv = ctxf[k];
          unsigned int wp = w1u[(size_t)(HID + k) * 256 + tid];
          a0 += cv * b2f((unsigned short)wp);
          a1 += cv * b2f((unsigned short)(wp >> 16));
        }
        zl[2 * tid] = f2b(tanhf(a0));
        zl[2 * tid + 1] = f2b(tanhf(a1));
      }
      __syncthreads();

      // dec_out[m] = z @ W2 ; write d_out row + next xdec
      {
        float a = 0.f;
        for (int k = 0; k < HID; ++k)
          a += b2f(zl[k]) * b2f(W2p[(size_t)k * EDIM + tid]);
        stf(dout, ((size_t)b * TG + i) * EDIM + tid, a, f32f);
        unsigned short xb = f2b(a);
        int ob = __shfl_xor((int)xb, 1);
        float ev = ldf(emb, (size_t)(SPECIAL + i + 1) * EDIM + tid, f32f);
        unsigned short eb = f2b(ev);
        int oe = __shfl_xor((int)eb, 1);
        if (!(tid & 1)) {
          unsigned int* xu = (unsigned int*)xdec;
          ast(xu + b * 256 + 128 + (tid >> 1),
              (unsigned int)xb | ((unsigned int)(ob & 0xffff) << 16));
          ast(xu + b * 256 + (tid >> 1),
              (unsigned int)eb | ((unsigned int)(oe & 0xffff) << 16));
        }
      }
    }
    gbar();   // xdec complete -> next step's cell may read
  }
}

__global__ __launch_bounds__(256) void attn_mm_k(
    const unsigned short* __restrict__ outF, const unsigned short* __restrict__ outB,
    const unsigned short* __restrict__ pkwm, unsigned short* __restrict__ att) {
  __shared__ char ldsA[4 * 1040];
  int bid = blockIdx.x;
  int bn = bid & 7, bm = bid >> 3;
  int tid = threadIdx.x, lane = tid & 63, wv = tid >> 6;
  int r0 = bm * 64;
  f32x4 acc[2][2] = {};
  int srow = tid >> 2, skb = tid & 3;
  int mt0 = (wv & 1) * 2, nt0 = (wv >> 1) * 2;
  for (int kk = 0; kk < 32; ++kk) {
    int kg = kk * 32 + skb * 8;
    const unsigned short* src = (kg < HID)
        ? (outF + (size_t)(r0 + srow) * HID + kg)
        : (outB + (size_t)(r0 + srow) * HID + (kg - HID));
    uint4 v = *(const uint4*)src;
    __syncthreads();
    *(uint4*)(ldsA + skb * 1040 + srow * 16) = v;
    __syncthreads();
    bf16x8 a[2], bb[2];
#pragma unroll
    for (int mi = 0; mi < 2; ++mi) {
      int rl = (mt0 + mi) * 16 + (lane & 15);
      a[mi] = *(const bf16x8*)(ldsA + (lane >> 4) * 1040 + rl * 16);
    }
#pragma unroll
    for (int nj = 0; nj < 2; ++nj) {
      int ntg = bn * 4 + nt0 + nj;
      bb[nj] = *(const bf16x8*)(pkwm + ((size_t)(ntg * 32 + kk) * 64 + lane) * 8);
    }
#pragma unroll
    for (int mi = 0; mi < 2; ++mi)
#pragma unroll
      for (int nj = 0; nj < 2; ++nj)
        acc[mi][nj] = __builtin_amdgcn_mfma_f32_16x16x32_bf16(a[mi], bb[nj], acc[mi][nj], 0, 0, 0);
  }
#pragma unroll
  for (int mi = 0; mi < 2; ++mi)
#pragma unroll
    for (int nj = 0; nj < 2; ++nj)
#pragma unroll
      for (int r = 0; r < 4; ++r) {
        int row = r0 + (mt0 + mi) * 16 + (lane >> 4) * 4 + r;
        int t = row >> 5, b = row & 31;
        int h = bn * 64 + (nt0 + nj) * 16 + (lane & 15);
        att[((size_t)b * TS + t) * HID + h] = f2b(acc[mi][nj][r]);
      }
}

__global__ void init_states_k(const void* __restrict__ ih, const void* __restrict__ ic,
                              unsigned short* hIF, unsigned short* hIB,
                              float* cF, float* cB, int* bar, const int* dtf) {
  int f32f = dtf[0];
  int g = blockIdx.x * 256 + threadIdx.x;
  if (g < (64 + 32) * FLAG_STRIDE)
    __hip_atomic_store(bar + g, 0, __ATOMIC_RELAXED, __HIP_MEMORY_SCOPE_AGENT);
  int b = g >> 9, j = g & 511;
  hIF[b * HID + j] = f2b(ldf(ih, j, f32f));
  hIB[b * HID + j] = f2b(ldf(ih, HID + j, f32f));
  cF[b * HID + j] = ldf(ic, j, f32f);
  cB[b * HID + j] = ldf(ic, HID + j, f32f);
}

__global__ void seqmean_k(const unsigned short* __restrict__ att,
                          const int* __restrict__ lens, float* __restrict__ sm) {
  int b = blockIdx.x, tid = threadIdx.x;
  int len = lens[b];
  float a0 = 0.f, a1 = 0.f;
  for (int t = 0; t < len; ++t) {
    const unsigned short* row = att + ((size_t)b * TS + t) * HID;
    a0 += b2f(row[tid]);
    a1 += b2f(row[tid + 256]);
  }
  float fl = (float)len;
  sm[b * HID + tid] = a0 / fl;
  sm[b * HID + tid + 256] = a1 / fl;
}

__global__ void mv_bb_k(const unsigned short* __restrict__ A1,
                        const unsigned short* __restrict__ A2,
                        const void* __restrict__ W, unsigned short* __restrict__ o,
                        const int* dtf) {
  int f32f = dtf[0];
  int g = blockIdx.x * 256 + threadIdx.x;
  int b = g >> 9, n = g & 511;
  float acc = 0.f;
  for (int k = 0; k < HID; ++k) acc += b2f(A1[b * HID + k]) * ldf(W, (size_t)k * HID + n, f32f);
  for (int k = 0; k < HID; ++k) acc += b2f(A2[b * HID + k]) * ldf(W, (size_t)(HID + k) * HID + n, f32f);
  o[b * HID + n] = f2b(acc);
}

__global__ void mv_ff_k(const float* __restrict__ A1, const float* __restrict__ A2,
                        const void* __restrict__ W, float* __restrict__ o, const int* dtf) {
  int f32f = dtf[0];
  int g = blockIdx.x * 256 + threadIdx.x;
  int b = g >> 9, n = g & 511;
  float acc = 0.f;
  for (int k = 0; k < HID; ++k) acc += A1[b * HID + k] * ldf(W, (size_t)k * HID + n, f32f);
  for (int k = 0; k < HID; ++k) acc += A2[b * HID + k] * ldf(W, (size_t)(HID + k) * HID + n, f32f);
  o[b * HID + n] = acc;
}

__global__ void proj1_k(const unsigned short* __restrict__ A1, const float* __restrict__ A2,
                        const void* __restrict__ W1p, const void* __restrict__ b1p,
                        unsigned short* __restrict__ z, const int* dtf) {
  int f32f = dtf[0];
  int g = blockIdx.x * 256 + threadIdx.x;
  int b = g >> 9, n = g & 511;
  float acc = ldf(b1p, n, f32f);
  for (int k = 0; k < HID; ++k) acc += b2f(A1[b * HID + k]) * ldf(W1p, (size_t)k * HID + n, f32f);
  for (int k = 0; k < HID; ++k) acc += A2[b * HID + k] * ldf(W1p, (size_t)(HID + k) * HID + n, f32f);
  z[b * HID + n] = f2b(tanhf(acc));
}

__global__ void proj2_init_k(const unsigned short* __restrict__ z,
                             const void* __restrict__ W2, const void* __restrict__ emb,
                             unsigned short* __restrict__ xdec, const int* dtf) {
  int f32f = dtf[0];
  int g = blockIdx.x * 256 + threadIdx.x;
  int b = g >> 8, n = g & 255;
  float acc = 0.f;
  for (int k = 0; k < HID; ++k) acc += b2f(z[b * HID + k]) * ldf(W2, (size_t)k * EDIM + n, f32f);
  xdec[b * HID + EDIM + n] = f2b(acc);
  xdec[b * HID + n] = f2b(ldf(emb, (size_t)SPECIAL * EDIM + n, f32f));
}

extern "C" void kernel_launch(void* const* d_in, const int* in_sizes, int n_in,
                              void* d_out, int out_size, void* d_ws, size_t ws_size,
                              hipStream_t stream) {
  (void)in_sizes; (void)n_in;
  const void* article = d_in[0];
  const int* art_lens = (const int*)d_in[1];
  const void* emb  = d_in[3];
  const void* eWxf = d_in[4]; const void* eWhf = d_in[5]; const void* ebf = d_in[6];
  const void* eWxb = d_in[7]; const void* eWhb = d_in[8]; const void* ebb = d_in[9];
  const void* initH = d_in[10]; const void* initC = d_in[11];
  const void* dhW = d_in[12]; const void* dcW = d_in[13];
  const void* wm = d_in[14]; const void* wq = d_in[15];
  const void* W1 = d_in[16]; const void* b1 = d_in[17]; const void* W2 = d_in[18];
  const void* dWx = d_in[19]; const void* dWh = d_in[20]; const void* db = d_in[21];

  char* ws = (char*)d_ws;
  size_t off = 0;
  auto take = [&](size_t bytes) -> char* {
    char* p = ws + off;
    off = (off + bytes + 255) & ~(size_t)255;
    return p;
  };
  int* dtf = (int*)take(4);
  int* bar = (int*)take((64 + 32) * FLAG_STRIDE * 4);
  unsigned short* pk_exf = (unsigned short*)take((size_t)GD * HID * 2);
  unsigned short* pk_ehf = (unsigned short*)take((size_t)GD * HID * 2);
  unsigned short* pk_exb = (unsigned short*)take((size_t)GD * HID * 2);
  unsigned short* pk_ehb = (unsigned short*)take((size_t)GD * HID * 2);
  unsigned short* pk_dx  = (unsigned short*)take((size_t)GD * HID * 2);
  unsigned short* pk_dh  = (unsigned short*)take((size_t)GD * HID * 2);
  unsigned short* pk_wm  = (unsigned short*)take((size_t)1024 * HID * 2);
  unsigned short* wqp = (unsigned short*)take((size_t)HID * HID * 2);
  unsigned short* W1p = (unsigned short*)take((size_t)2 * HID * HID * 2);
  unsigned short* b1p = (unsigned short*)take((size_t)HID * 2);
  unsigned short* W2p = (unsigned short*)take((size_t)HID * EDIM * 2);
  unsigned short* outF = (unsigned short*)take((size_t)TS * BATCH * HID * 2);
  unsigned short* outB = (unsigned short*)take((size_t)TS * BATCH * HID * 2);
  unsigned short* att  = (unsigned short*)take((size_t)BATCH * TS * HID * 2);
  unsigned short* hIF  = (unsigned short*)take((size_t)BATCH * HID * 2);
  unsigned short* hIB  = (unsigned short*)take((size_t)BATCH * HID * 2);
  float* cF = (float*)take((size_t)BATCH * HID * 4);
  float* cB = (float*)take((size_t)BATCH * HID * 4);
  unsigned short* hd0 = (unsigned short*)take((size_t)BATCH * HID * 2);
  unsigned short* hd1 = (unsigned short*)take((size_t)BATCH * HID * 2);
  float* cdec = (float*)take((size_t)BATCH * HID * 4);
  unsigned short* xdec = (unsigned short*)take((size_t)BATCH * HID * 2);
  unsigned short* zbuf = (unsigned short*)take((size_t)BATCH * HID * 2);
  float* sm = (float*)take((size_t)BATCH * HID * 4);

  if (off > ws_size) {
    fill_sig_k<<<(out_size + 255) / 256, 256, 0, stream>>>((unsigned short*)d_out, out_size);
    return;
  }

  detect_k<<<1, 256, 0, stream>>>(article, dtf);
  pack_gate_k<<<512, 256, 0, stream>>>(eWxf, pk_exf, dtf);
  pack_gate_k<<<512, 256, 0, stream>>>(eWhf, pk_ehf, dtf);
  pack_gate_k<<<512, 256, 0, stream>>>(eWxb, pk_exb, dtf);
  pack_gate_k<<<512, 256, 0, stream>>>(eWhb, pk_ehb, dtf);
  pack_gate_k<<<512, 256, 0, stream>>>(dWx, pk_dx, dtf);
  pack_gate_k<<<512, 256, 0, stream>>>(dWh, pk_dh, dtf);
  pack_wm_k<<<256, 256, 0, stream>>>(wm, pk_wm, dtf);
  pack_bf16_k<<<1024, 256, 0, stream>>>(wq, wqp, HID * HID, dtf);
  pack_bf16_k<<<2048, 256, 0, stream>>>(W1, W1p, 2 * HID * HID, dtf);
  pack_bf16_k<<<2, 256, 0, stream>>>(b1, b1p, HID, dtf);
  pack_bf16_k<<<512, 256, 0, stream>>>(W2, W2p, HID * EDIM, dtf);
  init_states_k<<<64, 256, 0, stream>>>(initH, initC, hIF, hIB, cF, cB, bar, dtf);

  enc_all_k<<<64, 256, 0, stream>>>(article, outF, outB, hIF, hIB, cF, cB,
                                    pk_exf, pk_ehf, pk_exb, pk_ehb, ebf, ebb,
                                    bar, dtf);

  attn_mm_k<<<4096, 256, 0, stream>>>(outF, outB, pk_wm, att);
  seqmean_k<<<32, 256, 0, stream>>>(att, art_lens, sm);
  mv_bb_k<<<64, 256, 0, stream>>>(outF + (size_t)(TS - 1) * BATCH * HID, outB, dhW, hd0, dtf);
  mv_ff_k<<<64, 256, 0, stream>>>(cF, cB, dcW, cdec, dtf);
  proj1_k<<<64, 256, 0, stream>>>(hd0, sm, W1, b1, zbuf, dtf);
  proj2_init_k<<<32, 256, 0, stream>>>(zbuf, W2, emb, xdec, dtf);

  // ---- decoder: ONE persistent dispatch, 32 blocks, 2 barriers/step ----
  dec_all_k<<<32, 256, 0, stream>>>(xdec, hd0, hd1, cdec, pk_dx, pk_dh, db,
                                    att, wqp, W1p, b1p, W2p, emb, art_lens,
                                    d_out, bar + 64 * FLAG_STRIDE, dtf);
}

// Round 9
// 15661.006 us; speedup vs baseline: 3.0345x; 3.0345x over previous
//
#include <hip/hip_runtime.h>

// Seq2Seq forward. R9: R8's 32-block/2-barrier decoder kept, but Phase B's
// serial GEMV loops (2560 latency-exposed loads/step = 634us/step measured,
// VALUBusy 0.6%) rewritten for memory-level parallelism: thread-contiguous
// weight packs (wqt/W1t/W2t) + uint4/bf16x8 vector loads + unroll-8, and
// score/context unrolled x4 rows with independent accumulators.

#define DI __device__ __forceinline__

constexpr int BATCH = 32;
constexpr int TS = 1024;
constexpr int TG = 64;
constexpr int HID = 512;
constexpr int GD = 2048;
constexpr int EDIM = 256;
constexpr int SPECIAL = 4;
constexpr size_t OFF_H = (size_t)BATCH * TG * EDIM;
constexpr size_t OFF_C = OFF_H + (size_t)BATCH * TG * HID;
constexpr int FLAG_STRIDE = 16;   // dwords (64B) per flag

typedef __attribute__((ext_vector_type(8))) short bf16x8;
typedef __attribute__((ext_vector_type(4))) float f32x4;

DI float b2f(unsigned short u) {
  union { unsigned int i; float f; } v; v.i = ((unsigned int)u) << 16; return v.f;
}
DI unsigned short f2b(float f) {
  union { float f; unsigned int i; } v; v.f = f;
  unsigned int r = v.i + 0x7fffu + ((v.i >> 16) & 1u);
  return (unsigned short)(r >> 16);
}
DI float sigm(float x) { return 1.0f / (1.0f + expf(-x)); }
DI float ldf(const void* p, size_t i, int f32f) {
  return f32f ? ((const float*)p)[i] : b2f(((const unsigned short*)p)[i]);
}
DI void stf(void* p, size_t i, float v, int f32f) {
  if (f32f) ((float*)p)[i] = v; else ((unsigned short*)p)[i] = f2b(v);
}
DI unsigned int ald(const unsigned int* p) {
  return __hip_atomic_load(p, __ATOMIC_RELAXED, __HIP_MEMORY_SCOPE_AGENT);
}
DI void ast(unsigned int* p, unsigned int v) {
  __hip_atomic_store(p, v, __ATOMIC_RELAXED, __HIP_MEMORY_SCOPE_AGENT);
}

__global__ void detect_k(const void* art, int* flag) {
  int tid = threadIdx.x;
  float x = ((const float*)art)[tid + 1024];
  float a = fabsf(x);
  int sane = (x == 0.0f) || (a > 1e-8f && a < 1e4f);
  unsigned long long m = __ballot(sane);
  __shared__ int cnt[4];
  if ((tid & 63) == 0) cnt[tid >> 6] = __popcll(m);
  __syncthreads();
  if (tid == 0) flag[0] = (cnt[0] + cnt[1] + cnt[2] + cnt[3] > 128) ? 1 : 0;
}

__global__ void fill_sig_k(unsigned short* o, int n) {
  int g = blockIdx.x * 256 + threadIdx.x;
  if (g < n) o[g] = 0x42F6;
}

__global__ void pack_gate_k(const void* __restrict__ W,
                            unsigned short* __restrict__ pk, const int* dtf) {
  int f32f = dtf[0];
  int g = blockIdx.x * 256 + threadIdx.x;
  if (g >= (GD * HID) / 8) return;
  int lane = g & 63;
  int kk = (g >> 6) & 15;
  int tile = g >> 10;
  int p = tile * 16 + (lane & 15);
  int nloc = p & 63, blk = p >> 6;
  int orow = (nloc >> 4) * HID + blk * 16 + (nloc & 15);
  int k = kk * 32 + (lane >> 4) * 8;
  unsigned short tmp[8];
#pragma unroll
  for (int j = 0; j < 8; ++j) tmp[j] = f2b(ldf(W, (size_t)orow * HID + k + j, f32f));
  *(uint4*)(pk + (size_t)g * 8) = *(uint4*)tmp;
}

__global__ void pack_wm_k(const void* __restrict__ wm,
                          unsigned short* __restrict__ pk, const int* dtf) {
  int f32f = dtf[0];
  int g = blockIdx.x * 256 + threadIdx.x;
  if (g >= 32 * 32 * 64) return;
  int lane = g & 63;
  int kk = (g >> 6) & 31;
  int nt = g >> 11;
  int col = nt * 16 + (lane & 15);
  int kb = kk * 32 + (lane >> 4) * 8;
  unsigned short tmp[8];
#pragma unroll
  for (int j = 0; j < 8; ++j) tmp[j] = f2b(ldf(wm, (size_t)(kb + j) * HID + col, f32f));
  *(uint4*)(pk + (size_t)g * 8) = *(uint4*)tmp;
}

__global__ void pack_bf16_k(const void* __restrict__ src,
                            unsigned short* __restrict__ dst, int n, const int* dtf) {
  int f32f = dtf[0];
  int g = blockIdx.x * 256 + threadIdx.x;
  if (g < n) dst[g] = f2b(ldf(src, g, f32f));
}

// wq [512k][512n] -> wqt[pair p][k] dword = (wq[k][2p], wq[k][2p+1])
__global__ void pack_wqt_k(const void* __restrict__ wq,
                           unsigned int* __restrict__ wqt, const int* dtf) {
  int f32f = dtf[0];
  int g = blockIdx.x * 256 + threadIdx.x;    // 512 blocks -> 131072
  if (g >= 256 * 512) return;
  int p = g >> 9, k = g & 511;
  unsigned int lo = f2b(ldf(wq, (size_t)k * HID + 2 * p, f32f));
  unsigned int hi = f2b(ldf(wq, (size_t)k * HID + 2 * p + 1, f32f));
  wqt[(size_t)p * 512 + k] = lo | (hi << 16);
}

// W1 [1024k][512n] -> W1t[pair p][k] dword
__global__ void pack_w1t_k(const void* __restrict__ W1,
                           unsigned int* __restrict__ W1t, const int* dtf) {
  int f32f = dtf[0];
  int g = blockIdx.x * 256 + threadIdx.x;    // 1024 blocks -> 262144
  if (g >= 256 * 1024) return;
  int p = g >> 10, k = g & 1023;
  unsigned int lo = f2b(ldf(W1, (size_t)k * HID + 2 * p, f32f));
  unsigned int hi = f2b(ldf(W1, (size_t)k * HID + 2 * p + 1, f32f));
  W1t[(size_t)p * 1024 + k] = lo | (hi << 16);
}

// W2 [512k][256n] -> W2t[col c][k] bf16
__global__ void pack_w2t_k(const void* __restrict__ W2,
                           unsigned short* __restrict__ W2t, const int* dtf) {
  int f32f = dtf[0];
  int g = blockIdx.x * 256 + threadIdx.x;    // 512 blocks -> 131072
  if (g >= 256 * 512) return;
  int c = g >> 9, k = g & 511;
  W2t[(size_t)c * 512 + k] = f2b(ldf(W2, (size_t)k * EDIM + c, f32f));
}

// ---------------------------------------------------------------------------
// Persistent bidirectional encoder (unchanged — proven).
// ---------------------------------------------------------------------------
__global__ __launch_bounds__(256, 1) void enc_all_k(
    const void* __restrict__ article,
    unsigned short* __restrict__ outF, unsigned short* __restrict__ outB,
    const unsigned short* __restrict__ hIF, const unsigned short* __restrict__ hIB,
    float* __restrict__ cF, float* __restrict__ cB,
    const unsigned short* __restrict__ pkXF, const unsigned short* __restrict__ pkHF,
    const unsigned short* __restrict__ pkXB, const unsigned short* __restrict__ pkHB,
    const void* __restrict__ bF, const void* __restrict__ bB,
    int* __restrict__ bar, const int* dtf) {
  const int f32f = dtf[0];
  const int blk = blockIdx.x;
  const int dir = blk >> 5;
  const int blk16 = blk & 31;
  const int tid = threadIdx.x;
  const int lane = tid & 63;
  const int wv = tid >> 6;
  const int tile = blk16 * 4 + wv;

  __shared__ unsigned short lstage[BATCH * HID];
  __shared__ float gbuf[BATCH * 68];

  const unsigned short* pkX = dir ? pkXB : pkXF;
  const unsigned short* pkH = dir ? pkHB : pkHF;
  const void* bias = dir ? bB : bF;
  unsigned short* out = dir ? outB : outF;
  const unsigned short* hI = dir ? hIB : hIF;
  float* cg = dir ? cB : cF;
  int* flp = bar + dir * 32 * FLAG_STRIDE;

  bf16x8 wx[16], wh[16];
  {
    const unsigned short* px = pkX + ((size_t)tile * 16 * 64 + lane) * 8;
    const unsigned short* ph = pkH + ((size_t)tile * 16 * 64 + lane) * 8;
#pragma unroll
    for (int kk = 0; kk < 16; ++kk) {
      wx[kk] = *(const bf16x8*)(px + (size_t)kk * 64 * 8);
      wh[kk] = *(const bf16x8*)(ph + (size_t)kk * 64 * 8);
    }
  }
  const int gb = tid >> 3;
  const int gj = (tid & 7) * 2;
  float c0 = cg[gb * HID + blk16 * 16 + gj];
  float c1 = cg[gb * HID + blk16 * 16 + gj + 1];

  const int r0 = lane & 15;
  const int r1 = 16 + r0;
  const int kbb = (lane >> 4) * 8;
  const int nloc = wv * 16 + (lane & 15);
  const int orow = (nloc >> 4) * HID + blk16 * 16 + (nloc & 15);
  const float bv = ldf(bias, orow, f32f);

  for (int t = 0; t < TS; ++t) {
    const int tsrc = dir ? (TS - 1 - t) : t;
#pragma unroll
    for (int it = 0; it < 8; ++it) {
      int ci = it * 256 + tid;
      int row = ci >> 6;
      int k8 = (ci & 63) << 3;
      unsigned off = (unsigned)(row * 1024 + ((k8 * 2) ^ ((row & 7) << 4)));
      if (f32f) {
        const float* s = (const float*)article + (size_t)tsrc * BATCH * HID +
                         (size_t)row * HID + k8;
        float4 u0 = *(const float4*)s;
        float4 u1 = *(const float4*)(s + 4);
        unsigned short tmp[8] = {f2b(u0.x), f2b(u0.y), f2b(u0.z), f2b(u0.w),
                                 f2b(u1.x), f2b(u1.y), f2b(u1.z), f2b(u1.w)};
        *(uint4*)((char*)lstage + off) = *(uint4*)tmp;
      } else {
        const unsigned short* s = (const unsigned short*)article +
                                  (size_t)tsrc * BATCH * HID + (size_t)row * HID + k8;
        *(uint4*)((char*)lstage + off) = *(const uint4*)s;
      }
    }
    __syncthreads();
    unsigned int* hu = (t == 0)
        ? (unsigned int*)hI
        : (unsigned int*)(out + (size_t)(tsrc + (dir ? 1 : -1)) * BATCH * HID);
    unsigned int hreg[32];
#pragma unroll
    for (int it = 0; it < 32; ++it) hreg[it] = ald(hu + it * 256 + tid);
    f32x4 acc0 = {0.f, 0.f, 0.f, 0.f};
    f32x4 acc1 = {0.f, 0.f, 0.f, 0.f};
#pragma unroll
    for (int kk = 0; kk < 16; ++kk) {
      unsigned o0 = (unsigned)(r0 * 1024 + (((kk * 32 + kbb) * 2) ^ ((r0 & 7) << 4)));
      unsigned o1 = (unsigned)(r1 * 1024 + (((kk * 32 + kbb) * 2) ^ ((r0 & 7) << 4)));
      bf16x8 a0 = *(const bf16x8*)((const char*)lstage + o0);
      bf16x8 a1 = *(const bf16x8*)((const char*)lstage + o1);
      acc0 = __builtin_amdgcn_mfma_f32_16x16x32_bf16(a0, wx[kk], acc0, 0, 0, 0);
      acc1 = __builtin_amdgcn_mfma_f32_16x16x32_bf16(a1, wx[kk], acc1, 0, 0, 0);
    }
    __syncthreads();
#pragma unroll
    for (int it = 0; it < 32; ++it) {
      int dw = it * 256 + tid;
      int row = dw >> 8;
      unsigned lb = (unsigned)(row * 1024 +
                               (((dw & 252) << 2) ^ ((row & 7) << 4)) +
                               ((dw & 3) << 2));
      *(unsigned int*)((char*)lstage + lb) = hreg[it];
    }
    __syncthreads();
#pragma unroll
    for (int kk = 0; kk < 16; ++kk) {
      unsigned o0 = (unsigned)(r0 * 1024 + (((kk * 32 + kbb) * 2) ^ ((r0 & 7) << 4)));
      unsigned o1 = (unsigned)(r1 * 1024 + (((kk * 32 + kbb) * 2) ^ ((r0 & 7) << 4)));
      bf16x8 a0 = *(const bf16x8*)((const char*)lstage + o0);
      bf16x8 a1 = *(const bf16x8*)((const char*)lstage + o1);
      acc0 = __builtin_amdgcn_mfma_f32_16x16x32_bf16(a0, wh[kk], acc0, 0, 0, 0);
      acc1 = __builtin_amdgcn_mfma_f32_16x16x32_bf16(a1, wh[kk], acc1, 0, 0, 0);
    }
#pragma unroll
    for (int r = 0; r < 4; ++r) {
      int brow = (lane >> 4) * 4 + r;
      gbuf[brow * 68 + nloc] = acc0[r] + bv;
      gbuf[(16 + brow) * 68 + nloc] = acc1[r] + bv;
    }
    __syncthreads();
    {
      float gi0 = gbuf[gb * 68 + gj],      gf0 = gbuf[gb * 68 + 16 + gj];
      float gg0 = gbuf[gb * 68 + 32 + gj], go0 = gbuf[gb * 68 + 48 + gj];
      float gi1 = gbuf[gb * 68 + gj + 1],      gf1 = gbuf[gb * 68 + 16 + gj + 1];
      float gg1 = gbuf[gb * 68 + 32 + gj + 1], go1 = gbuf[gb * 68 + 48 + gj + 1];
      float cn0 = sigm(gf0) * c0 + sigm(gi0) * tanhf(gg0); c0 = cn0;
      float cn1 = sigm(gf1) * c1 + sigm(gi1) * tanhf(gg1); c1 = cn1;
      unsigned int hv = (unsigned int)f2b(sigm(go0) * tanhf(cn0)) |
                        ((unsigned int)f2b(sigm(go1) * tanhf(cn1)) << 16);
      ast((unsigned int*)out + (size_t)tsrc * (BATCH * HID / 2) +
              gb * (HID / 2) + blk16 * 8 + (tid & 7), hv);
    }
    if (t + 1 < TS) {
      __syncthreads();
      if (wv == 0) {
        const int target = t + 1;
        if (lane == 0)
          __hip_atomic_store(flp + blk16 * FLAG_STRIDE, target,
                             __ATOMIC_RELAXED, __HIP_MEMORY_SCOPE_AGENT);
        for (;;) {
          int v = (lane < 32)
              ? __hip_atomic_load(flp + lane * FLAG_STRIDE, __ATOMIC_RELAXED,
                                  __HIP_MEMORY_SCOPE_AGENT)
              : 0x7fffffff;
          if (__all(v >= target)) break;
          __builtin_amdgcn_s_sleep(2);
        }
      }
      __syncthreads();
    }
  }
  cg[gb * HID + blk16 * 16 + gj] = c0;
  cg[gb * HID + blk16 * 16 + gj + 1] = c1;
}

// ---------------------------------------------------------------------------
// Persistent fused decoder: 32 blocks, 2 grid barriers/step; Phase B with
// thread-contiguous weight streams + deep unrolling for MLP.
// ---------------------------------------------------------------------------
__global__ __launch_bounds__(256, 1) void dec_all_k(
    unsigned short* __restrict__ xdec,
    unsigned short* __restrict__ hd0, unsigned short* __restrict__ hd1,
    const float* __restrict__ cdec,
    const unsigned short* __restrict__ pkX, const unsigned short* __restrict__ pkH,
    const void* __restrict__ dbias,
    const unsigned short* __restrict__ att,
    const unsigned int* __restrict__ wqt,     // [256 pair][512 k] dwords
    const unsigned int* __restrict__ W1t,     // [256 pair][1024 k] dwords
    const unsigned short* __restrict__ b1p,   // bf16 [512]
    const unsigned short* __restrict__ W2t,   // [256 col][512 k] bf16
    const void* __restrict__ emb, const int* __restrict__ lens,
    void* __restrict__ dout,
    int* __restrict__ flags, const int* dtf) {
  const int f32f = dtf[0];
  const int blk = blockIdx.x;       // 0..31
  const int tid = threadIdx.x;
  const int lane = tid & 63;
  const int wv = tid >> 6;
  __shared__ __align__(16) char smem[49152];

  const int gb = tid >> 3;
  const int gj = (tid & 7) * 2;
  const int r0 = lane & 15;
  const int r1 = 16 + r0;
  const int kbb = (lane >> 4) * 8;
  const int nloc = wv * 16 + (lane & 15);
  float c0 = cdec[gb * HID + blk * 16 + gj];
  float c1 = cdec[gb * HID + blk * 16 + gj + 1];
  const int orow = (nloc >> 4) * HID + blk * 16 + (nloc & 15);
  const float bv = ldf(dbias, orow, f32f);

  int ep = 0;
  auto gbar = [&]() {
    __syncthreads();   // vmcnt(0) drain: agent stores globally complete
    ++ep;
    if (wv == 0) {
      if (lane == 0)
        __hip_atomic_store(flags + blk * FLAG_STRIDE, ep, __ATOMIC_RELAXED,
                           __HIP_MEMORY_SCOPE_AGENT);
      for (;;) {
        int v = (lane < 32)
            ? __hip_atomic_load(flags + lane * FLAG_STRIDE, __ATOMIC_RELAXED,
                                __HIP_MEMORY_SCOPE_AGENT)
            : 0x7fffffff;
        if (__all(v >= ep)) break;
        __builtin_amdgcn_s_sleep(2);
      }
    }
    __syncthreads();
  };

  for (int i = 0; i < TG; ++i) {
    unsigned short* hin = (i & 1) ? hd1 : hd0;
    unsigned short* hout = (i & 1) ? hd0 : hd1;

    // ================= Phase A: LSTM cell =================
    {
      unsigned short* lstage = (unsigned short*)smem;
      float* gbuf = (float*)(smem + 32768);
      const unsigned int* xu = (const unsigned int*)xdec;
      unsigned int xreg[32];
#pragma unroll
      for (int it = 0; it < 32; ++it) xreg[it] = ald(xu + it * 256 + tid);
#pragma unroll
      for (int it = 0; it < 32; ++it) {
        int dw = it * 256 + tid;
        int row = dw >> 8;
        unsigned lb = (unsigned)(row * 1024 +
                                 (((dw & 252) << 2) ^ ((row & 7) << 4)) +
                                 ((dw & 3) << 2));
        *(unsigned int*)((char*)lstage + lb) = xreg[it];
      }
      __syncthreads();
      const unsigned int* hu = (const unsigned int*)hin;
      unsigned int hreg[32];
#pragma unroll
      for (int it = 0; it < 32; ++it) hreg[it] = ald(hu + it * 256 + tid);
      const int tile = blk * 4 + wv;
      const unsigned short* pwx = pkX + (size_t)tile * 16 * 64 * 8;
      const unsigned short* pwh = pkH + (size_t)tile * 16 * 64 * 8;
      f32x4 acc0 = {0.f, 0.f, 0.f, 0.f};
      f32x4 acc1 = {0.f, 0.f, 0.f, 0.f};
#pragma unroll
      for (int kk = 0; kk < 16; ++kk) {
        unsigned o0 = (unsigned)(r0 * 1024 + (((kk * 32 + kbb) * 2) ^ ((r0 & 7) << 4)));
        unsigned o1 = (unsigned)(r1 * 1024 + (((kk * 32 + kbb) * 2) ^ ((r0 & 7) << 4)));
        bf16x8 a0 = *(const bf16x8*)((const char*)lstage + o0);
        bf16x8 a1 = *(const bf16x8*)((const char*)lstage + o1);
        bf16x8 bb = *(const bf16x8*)(pwx + (size_t)(kk * 64 + lane) * 8);
        acc0 = __builtin_amdgcn_mfma_f32_16x16x32_bf16(a0, bb, acc0, 0, 0, 0);
        acc1 = __builtin_amdgcn_mfma_f32_16x16x32_bf16(a1, bb, acc1, 0, 0, 0);
      }
      __syncthreads();
#pragma unroll
      for (int it = 0; it < 32; ++it) {
        int dw = it * 256 + tid;
        int row = dw >> 8;
        unsigned lb = (unsigned)(row * 1024 +
                                 (((dw & 252) << 2) ^ ((row & 7) << 4)) +
                                 ((dw & 3) << 2));
        *(unsigned int*)((char*)lstage + lb) = hreg[it];
      }
      __syncthreads();
#pragma unroll
      for (int kk = 0; kk < 16; ++kk) {
        unsigned o0 = (unsigned)(r0 * 1024 + (((kk * 32 + kbb) * 2) ^ ((r0 & 7) << 4)));
        unsigned o1 = (unsigned)(r1 * 1024 + (((kk * 32 + kbb) * 2) ^ ((r0 & 7) << 4)));
        bf16x8 a0 = *(const bf16x8*)((const char*)lstage + o0);
        bf16x8 a1 = *(const bf16x8*)((const char*)lstage + o1);
        bf16x8 bb = *(const bf16x8*)(pwh + (size_t)(kk * 64 + lane) * 8);
        acc0 = __builtin_amdgcn_mfma_f32_16x16x32_bf16(a0, bb, acc0, 0, 0, 0);
        acc1 = __builtin_amdgcn_mfma_f32_16x16x32_bf16(a1, bb, acc1, 0, 0, 0);
      }
#pragma unroll
      for (int r = 0; r < 4; ++r) {
        int brow = (lane >> 4) * 4 + r;
        gbuf[brow * 68 + nloc] = acc0[r] + bv;
        gbuf[(16 + brow) * 68 + nloc] = acc1[r] + bv;
      }
      __syncthreads();
      {
        float gi0 = gbuf[gb * 68 + gj],      gf0 = gbuf[gb * 68 + 16 + gj];
        float gg0 = gbuf[gb * 68 + 32 + gj], go0 = gbuf[gb * 68 + 48 + gj];
        float gi1 = gbuf[gb * 68 + gj + 1],      gf1 = gbuf[gb * 68 + 16 + gj + 1];
        float gg1 = gbuf[gb * 68 + 32 + gj + 1], go1 = gbuf[gb * 68 + 48 + gj + 1];
        float cn0 = sigm(gf0) * c0 + sigm(gi0) * tanhf(gg0); c0 = cn0;
        float cn1 = sigm(gf1) * c1 + sigm(gi1) * tanhf(gg1); c1 = cn1;
        float hn0 = sigm(go0) * tanhf(cn0);
        float hn1 = sigm(go1) * tanhf(cn1);
        ast((unsigned int*)hout + gb * (HID / 2) + blk * 8 + (tid & 7),
            (unsigned int)f2b(hn0) | ((unsigned int)f2b(hn1) << 16));
        size_t e0 = ((size_t)gb * TG + i) * HID + blk * 16 + gj;
        stf(dout, OFF_H + e0, hn0, f32f);
        stf(dout, OFF_H + e0 + 1, hn1, f32f);
        stf(dout, OFF_C + e0, cn0, f32f);
        stf(dout, OFF_C + e0 + 1, cn1, f32f);
      }
    }
    gbar();   // h complete

    // ================= Phase B: per-batch pipeline (block = batch b) =======
    {
      const int b = blk;
      const int len = lens[b];
      unsigned short* lhB = (unsigned short*)smem;            // [512] bf16
      float* qf   = (float*)(smem + 1024);                    // [512] f32
      float* sc   = (float*)(smem + 4096);                    // [1024] f32
      float* red  = (float*)(smem + 8192);                    // [256] f32
      float* cred = (float*)(smem + 12288);                   // [4][512] f32
      float* ctxf = (float*)(smem + 20480);                   // [512] f32
      unsigned short* zl = (unsigned short*)(smem + 22528);   // [512] bf16

      ((unsigned int*)lhB)[tid] = ald((const unsigned int*)hout + b * 256 + tid);
      __syncthreads();

      // query cols (2tid, 2tid+1): thread-contiguous wqt stream, uint4 loads
      {
        const uint4* wt = (const uint4*)(wqt + (size_t)tid * 512);
        const unsigned int* hu32 = (const unsigned int*)lhB;
        float a0 = 0.f, a1 = 0.f;
#pragma unroll 8
        for (int k4 = 0; k4 < 128; ++k4) {
          uint4 w = wt[k4];
          unsigned int h01 = hu32[2 * k4], h23 = hu32[2 * k4 + 1];
          float h0 = b2f((unsigned short)h01), h1 = b2f((unsigned short)(h01 >> 16));
          float h2 = b2f((unsigned short)h23), h3 = b2f((unsigned short)(h23 >> 16));
          a0 += h0 * b2f((unsigned short)w.x); a1 += h0 * b2f((unsigned short)(w.x >> 16));
          a0 += h1 * b2f((unsigned short)w.y); a1 += h1 * b2f((unsigned short)(w.y >> 16));
          a0 += h2 * b2f((unsigned short)w.z); a1 += h2 * b2f((unsigned short)(w.z >> 16));
          a0 += h3 * b2f((unsigned short)w.w); a1 += h3 * b2f((unsigned short)(w.w >> 16));
        }
        qf[2 * tid] = a0;
        qf[2 * tid + 1] = a1;
      }
      __syncthreads();

      // score: wave handles 256 rows, 4 at a time with independent sums
      {
        float qv[8];
#pragma unroll
        for (int j = 0; j < 8; ++j) qv[j] = qf[lane * 8 + j];
        const unsigned short* ab = att + ((size_t)b * TS + wv * 256) * HID + lane * 8;
#pragma unroll 2
        for (int tt = 0; tt < 256; tt += 4) {
          bf16x8 rr0 = *(const bf16x8*)(ab + (size_t)(tt + 0) * HID);
          bf16x8 rr1 = *(const bf16x8*)(ab + (size_t)(tt + 1) * HID);
          bf16x8 rr2 = *(const bf16x8*)(ab + (size_t)(tt + 2) * HID);
          bf16x8 rr3 = *(const bf16x8*)(ab + (size_t)(tt + 3) * HID);
          float s0 = 0.f, s1 = 0.f, s2 = 0.f, s3 = 0.f;
#pragma unroll
          for (int e = 0; e < 8; ++e) {
            s0 += qv[e] * b2f(((const unsigned short*)&rr0)[e]);
            s1 += qv[e] * b2f(((const unsigned short*)&rr1)[e]);
            s2 += qv[e] * b2f(((const unsigned short*)&rr2)[e]);
            s3 += qv[e] * b2f(((const unsigned short*)&rr3)[e]);
          }
          for (int o = 32; o; o >>= 1) {
            s0 += __shfl_xor(s0, o, 64); s1 += __shfl_xor(s1, o, 64);
            s2 += __shfl_xor(s2, o, 64); s3 += __shfl_xor(s3, o, 64);
          }
          if (lane == 0) {
            int t = wv * 256 + tt;
            sc[t] = s0; sc[t + 1] = s1; sc[t + 2] = s2; sc[t + 3] = s3;
          }
        }
      }
      __syncthreads();

      // softmax over sc[0..len) in place
      {
        float sv[4], mx = -1e30f;
#pragma unroll
        for (int q = 0; q < 4; ++q) {
          int t = q * 256 + tid;
          float v = (t < len) ? sc[t] : -1e30f;
          sv[q] = v; mx = fmaxf(mx, v);
        }
        red[tid] = mx; __syncthreads();
        for (int st = 128; st; st >>= 1) { if (tid < st) red[tid] = fmaxf(red[tid], red[tid + st]); __syncthreads(); }
        mx = red[0]; __syncthreads();
        float e[4], sum = 0.f;
#pragma unroll
        for (int q = 0; q < 4; ++q) { e[q] = (sv[q] > -1e29f) ? expf(sv[q] - mx) : 0.f; sum += e[q]; }
        red[tid] = sum; __syncthreads();
        for (int st = 128; st; st >>= 1) { if (tid < st) red[tid] += red[tid + st]; __syncthreads(); }
        sum = red[0]; __syncthreads();
#pragma unroll
        for (int q = 0; q < 4; ++q) sc[q * 256 + tid] = e[q] / sum;
      }
      __syncthreads();

      // context: wave wv sums t = wv::4, 4 rows per window
      {
        float ca[8] = {0.f, 0.f, 0.f, 0.f, 0.f, 0.f, 0.f, 0.f};
        const unsigned short* ab = att + (size_t)b * TS * HID + lane * 8;
#pragma unroll 2
        for (int jj = 0; jj < 256; jj += 4) {
          int t0 = wv + 4 * jj;
          bf16x8 rr0 = *(const bf16x8*)(ab + (size_t)(t0)      * HID);
          bf16x8 rr1 = *(const bf16x8*)(ab + (size_t)(t0 + 4)  * HID);
          bf16x8 rr2 = *(const bf16x8*)(ab + (size_t)(t0 + 8)  * HID);
          bf16x8 rr3 = *(const bf16x8*)(ab + (size_t)(t0 + 12) * HID);
          float p0 = sc[t0], p1 = sc[t0 + 4], p2 = sc[t0 + 8], p3 = sc[t0 + 12];
#pragma unroll
          for (int e = 0; e < 8; ++e) {
            float v = p0 * b2f(((const unsigned short*)&rr0)[e]);
            v += p1 * b2f(((const unsigned short*)&rr1)[e]);
            v += p2 * b2f(((const unsigned short*)&rr2)[e]);
            v += p3 * b2f(((const unsigned short*)&rr3)[e]);
            ca[e] += v;
          }
        }
#pragma unroll
        for (int e = 0; e < 8; ++e) cred[wv * 512 + lane * 8 + e] = ca[e];
      }
      __syncthreads();
      ctxf[tid] = cred[tid] + cred[512 + tid] + cred[1024 + tid] + cred[1536 + tid];
      ctxf[256 + tid] = cred[256 + tid] + cred[768 + tid] + cred[1280 + tid] + cred[1792 + tid];
      __syncthreads();

      // z cols (2tid,2tid+1): W1t stream (h part then ctx part)
      {
        float a0 = b2f(b1p[2 * tid]);
        float a1 = b2f(b1p[2 * tid + 1]);
        const uint4* wt = (const uint4*)(W1t + (size_t)tid * 1024);
        const unsigned int* hu32 = (const unsigned int*)lhB;
#pragma unroll 8
        for (int k4 = 0; k4 < 128; ++k4) {
          uint4 w = wt[k4];
          unsigned int h01 = hu32[2 * k4], h23 = hu32[2 * k4 + 1];
          float h0 = b2f((unsigned short)h01), h1 = b2f((unsigned short)(h01 >> 16));
          float h2 = b2f((unsigned short)h23), h3 = b2f((unsigned short)(h23 >> 16));
          a0 += h0 * b2f((unsigned short)w.x); a1 += h0 * b2f((unsigned short)(w.x >> 16));
          a0 += h1 * b2f((unsigned short)w.y); a1 += h1 * b2f((unsigned short)(w.y >> 16));
          a0 += h2 * b2f((unsigned short)w.z); a1 += h2 * b2f((unsigned short)(w.z >> 16));
          a0 += h3 * b2f((unsigned short)w.w); a1 += h3 * b2f((unsigned short)(w.w >> 16));
        }
        const uint4* wt2 = (const uint4*)(W1t + (size_t)tid * 1024 + 512);
#pragma unroll 8
        for (int k4 = 0; k4 < 128; ++k4) {
          uint4 w = wt2[k4];
          float h0 = ctxf[4 * k4], h1 = ctxf[4 * k4 + 1];
          float h2 = ctxf[4 * k4 + 2], h3 = ctxf[4 * k4 + 3];
          a0 += h0 * b2f((unsigned short)w.x); a1 += h0 * b2f((unsigned short)(w.x >> 16));
          a0 += h1 * b2f((unsigned short)w.y); a1 += h1 * b2f((unsigned short)(w.y >> 16));
          a0 += h2 * b2f((unsigned short)w.z); a1 += h2 * b2f((unsigned short)(w.z >> 16));
          a0 += h3 * b2f((unsigned short)w.w); a1 += h3 * b2f((unsigned short)(w.w >> 16));
        }
        zl[2 * tid] = f2b(tanhf(a0));
        zl[2 * tid + 1] = f2b(tanhf(a1));
      }
      __syncthreads();

      // dec_out[tid] = z @ W2t[tid]; write d_out row + next xdec
      {
        const bf16x8* wt = (const bf16x8*)(W2t + (size_t)tid * 512);
        float a = 0.f;
#pragma unroll 4
        for (int k8 = 0; k8 < 64; ++k8) {
          bf16x8 w = wt[k8];
          const unsigned short* zp = zl + k8 * 8;
#pragma unroll
          for (int e = 0; e < 8; ++e)
            a += b2f(zp[e]) * b2f(((const unsigned short*)&w)[e]);
        }
        stf(dout, ((size_t)b * TG + i) * EDIM + tid, a, f32f);
        unsigned short xb = f2b(a);
        int ob = __shfl_xor((int)xb, 1);
        float ev = ldf(emb, (size_t)(SPECIAL + i + 1) * EDIM + tid, f32f);
        unsigned short eb = f2b(ev);
        int oe = __shfl_xor((int)eb, 1);
        if (!(tid & 1)) {
          unsigned int* xu = (unsigned int*)xdec;
          ast(xu + b * 256 + 128 + (tid >> 1),
              (unsigned int)xb | ((unsigned int)(ob & 0xffff) << 16));
          ast(xu + b * 256 + (tid >> 1),
              (unsigned int)eb | ((unsigned int)(oe & 0xffff) << 16));
        }
      }
    }
    gbar();   // xdec complete
  }
}

__global__ __launch_bounds__(256) void attn_mm_k(
    const unsigned short* __restrict__ outF, const unsigned short* __restrict__ outB,
    const unsigned short* __restrict__ pkwm, unsigned short* __restrict__ att) {
  __shared__ char ldsA[4 * 1040];
  int bid = blockIdx.x;
  int bn = bid & 7, bm = bid >> 3;
  int tid = threadIdx.x, lane = tid & 63, wv = tid >> 6;
  int r0 = bm * 64;
  f32x4 acc[2][2] = {};
  int srow = tid >> 2, skb = tid & 3;
  int mt0 = (wv & 1) * 2, nt0 = (wv >> 1) * 2;
  for (int kk = 0; kk < 32; ++kk) {
    int kg = kk * 32 + skb * 8;
    const unsigned short* src = (kg < HID)
        ? (outF + (size_t)(r0 + srow) * HID + kg)
        : (outB + (size_t)(r0 + srow) * HID + (kg - HID));
    uint4 v = *(const uint4*)src;
    __syncthreads();
    *(uint4*)(ldsA + skb * 1040 + srow * 16) = v;
    __syncthreads();
    bf16x8 a[2], bb[2];
#pragma unroll
    for (int mi = 0; mi < 2; ++mi) {
      int rl = (mt0 + mi) * 16 + (lane & 15);
      a[mi] = *(const bf16x8*)(ldsA + (lane >> 4) * 1040 + rl * 16);
    }
#pragma unroll
    for (int nj = 0; nj < 2; ++nj) {
      int ntg = bn * 4 + nt0 + nj;
      bb[nj] = *(const bf16x8*)(pkwm + ((size_t)(ntg * 32 + kk) * 64 + lane) * 8);
    }
#pragma unroll
    for (int mi = 0; mi < 2; ++mi)
#pragma unroll
      for (int nj = 0; nj < 2; ++nj)
        acc[mi][nj] = __builtin_amdgcn_mfma_f32_16x16x32_bf16(a[mi], bb[nj], acc[mi][nj], 0, 0, 0);
  }
#pragma unroll
  for (int mi = 0; mi < 2; ++mi)
#pragma unroll
    for (int nj = 0; nj < 2; ++nj)
#pragma unroll
      for (int r = 0; r < 4; ++r) {
        int row = r0 + (mt0 + mi) * 16 + (lane >> 4) * 4 + r;
        int t = row >> 5, b = row & 31;
        int h = bn * 64 + (nt0 + nj) * 16 + (lane & 15);
        att[((size_t)b * TS + t) * HID + h] = f2b(acc[mi][nj][r]);
      }
}

__global__ void init_states_k(const void* __restrict__ ih, const void* __restrict__ ic,
                              unsigned short* hIF, unsigned short* hIB,
                              float* cF, float* cB, int* bar, const int* dtf) {
  int f32f = dtf[0];
  int g = blockIdx.x * 256 + threadIdx.x;
  if (g < (64 + 32) * FLAG_STRIDE)
    __hip_atomic_store(bar + g, 0, __ATOMIC_RELAXED, __HIP_MEMORY_SCOPE_AGENT);
  int b = g >> 9, j = g & 511;
  hIF[b * HID + j] = f2b(ldf(ih, j, f32f));
  hIB[b * HID + j] = f2b(ldf(ih, HID + j, f32f));
  cF[b * HID + j] = ldf(ic, j, f32f);
  cB[b * HID + j] = ldf(ic, HID + j, f32f);
}

__global__ void seqmean_k(const unsigned short* __restrict__ att,
                          const int* __restrict__ lens, float* __restrict__ sm) {
  int b = blockIdx.x, tid = threadIdx.x;
  int len = lens[b];
  float a0 = 0.f, a1 = 0.f;
  for (int t = 0; t < len; ++t) {
    const unsigned short* row = att + ((size_t)b * TS + t) * HID;
    a0 += b2f(row[tid]);
    a1 += b2f(row[tid + 256]);
  }
  float fl = (float)len;
  sm[b * HID + tid] = a0 / fl;
  sm[b * HID + tid + 256] = a1 / fl;
}

__global__ void mv_bb_k(const unsigned short* __restrict__ A1,
                        const unsigned short* __restrict__ A2,
                        const void* __restrict__ W, unsigned short* __restrict__ o,
                        const int* dtf) {
  int f32f = dtf[0];
  int g = blockIdx.x * 256 + threadIdx.x;
  int b = g >> 9, n = g & 511;
  float acc = 0.f;
  for (int k = 0; k < HID; ++k) acc += b2f(A1[b * HID + k]) * ldf(W, (size_t)k * HID + n, f32f);
  for (int k = 0; k < HID; ++k) acc += b2f(A2[b * HID + k]) * ldf(W, (size_t)(HID + k) * HID + n, f32f);
  o[b * HID + n] = f2b(acc);
}

__global__ void mv_ff_k(const float* __restrict__ A1, const float* __restrict__ A2,
                        const void* __restrict__ W, float* __restrict__ o, const int* dtf) {
  int f32f = dtf[0];
  int g = blockIdx.x * 256 + threadIdx.x;
  int b = g >> 9, n = g & 511;
  float acc = 0.f;
  for (int k = 0; k < HID; ++k) acc += A1[b * HID + k] * ldf(W, (size_t)k * HID + n, f32f);
  for (int k = 0; k < HID; ++k) acc += A2[b * HID + k] * ldf(W, (size_t)(HID + k) * HID + n, f32f);
  o[b * HID + n] = acc;
}

__global__ void proj1_k(const unsigned short* __restrict__ A1, const float* __restrict__ A2,
                        const void* __restrict__ W1p, const void* __restrict__ b1p,
                        unsigned short* __restrict__ z, const int* dtf) {
  int f32f = dtf[0];
  int g = blockIdx.x * 256 + threadIdx.x;
  int b = g >> 9, n = g & 511;
  float acc = ldf(b1p, n, f32f);
  for (int k = 0; k < HID; ++k) acc += b2f(A1[b * HID + k]) * ldf(W1p, (size_t)k * HID + n, f32f);
  for (int k = 0; k < HID; ++k) acc += A2[b * HID + k] * ldf(W1p, (size_t)(HID + k) * HID + n, f32f);
  z[b * HID + n] = f2b(tanhf(acc));
}

__global__ void proj2_init_k(const unsigned short* __restrict__ z,
                             const void* __restrict__ W2, const void* __restrict__ emb,
                             unsigned short* __restrict__ xdec, const int* dtf) {
  int f32f = dtf[0];
  int g = blockIdx.x * 256 + threadIdx.x;
  int b = g >> 8, n = g & 255;
  float acc = 0.f;
  for (int k = 0; k < HID; ++k) acc += b2f(z[b * HID + k]) * ldf(W2, (size_t)k * EDIM + n, f32f);
  xdec[b * HID + EDIM + n] = f2b(acc);
  xdec[b * HID + n] = f2b(ldf(emb, (size_t)SPECIAL * EDIM + n, f32f));
}

extern "C" void kernel_launch(void* const* d_in, const int* in_sizes, int n_in,
                              void* d_out, int out_size, void* d_ws, size_t ws_size,
                              hipStream_t stream) {
  (void)in_sizes; (void)n_in;
  const void* article = d_in[0];
  const int* art_lens = (const int*)d_in[1];
  const void* emb  = d_in[3];
  const void* eWxf = d_in[4]; const void* eWhf = d_in[5]; const void* ebf = d_in[6];
  const void* eWxb = d_in[7]; const void* eWhb = d_in[8]; const void* ebb = d_in[9];
  const void* initH = d_in[10]; const void* initC = d_in[11];
  const void* dhW = d_in[12]; const void* dcW = d_in[13];
  const void* wm = d_in[14]; const void* wq = d_in[15];
  const void* W1 = d_in[16]; const void* b1 = d_in[17]; const void* W2 = d_in[18];
  const void* dWx = d_in[19]; const void* dWh = d_in[20]; const void* db = d_in[21];

  char* ws = (char*)d_ws;
  size_t off = 0;
  auto take = [&](size_t bytes) -> char* {
    char* p = ws + off;
    off = (off + bytes + 255) & ~(size_t)255;
    return p;
  };
  int* dtf = (int*)take(4);
  int* bar = (int*)take((64 + 32) * FLAG_STRIDE * 4);
  unsigned short* pk_exf = (unsigned short*)take((size_t)GD * HID * 2);
  unsigned short* pk_ehf = (unsigned short*)take((size_t)GD * HID * 2);
  unsigned short* pk_exb = (unsigned short*)take((size_t)GD * HID * 2);
  unsigned short* pk_ehb = (unsigned short*)take((size_t)GD * HID * 2);
  unsigned short* pk_dx  = (unsigned short*)take((size_t)GD * HID * 2);
  unsigned short* pk_dh  = (unsigned short*)take((size_t)GD * HID * 2);
  unsigned short* pk_wm  = (unsigned short*)take((size_t)1024 * HID * 2);
  unsigned int* wqt = (unsigned int*)take((size_t)256 * 512 * 4);
  unsigned int* W1t = (unsigned int*)take((size_t)256 * 1024 * 4);
  unsigned short* b1p = (unsigned short*)take((size_t)HID * 2);
  unsigned short* W2t = (unsigned short*)take((size_t)256 * 512 * 2);
  unsigned short* outF = (unsigned short*)take((size_t)TS * BATCH * HID * 2);
  unsigned short* outB = (unsigned short*)take((size_t)TS * BATCH * HID * 2);
  unsigned short* att  = (unsigned short*)take((size_t)BATCH * TS * HID * 2);
  unsigned short* hIF  = (unsigned short*)take((size_t)BATCH * HID * 2);
  unsigned short* hIB  = (unsigned short*)take((size_t)BATCH * HID * 2);
  float* cF = (float*)take((size_t)BATCH * HID * 4);
  float* cB = (float*)take((size_t)BATCH * HID * 4);
  unsigned short* hd0 = (unsigned short*)take((size_t)BATCH * HID * 2);
  unsigned short* hd1 = (unsigned short*)take((size_t)BATCH * HID * 2);
  float* cdec = (float*)take((size_t)BATCH * HID * 4);
  unsigned short* xdec = (unsigned short*)take((size_t)BATCH * HID * 2);
  unsigned short* zbuf = (unsigned short*)take((size_t)BATCH * HID * 2);
  float* sm = (float*)take((size_t)BATCH * HID * 4);

  if (off > ws_size) {
    fill_sig_k<<<(out_size + 255) / 256, 256, 0, stream>>>((unsigned short*)d_out, out_size);
    return;
  }

  detect_k<<<1, 256, 0, stream>>>(article, dtf);
  pack_gate_k<<<512, 256, 0, stream>>>(eWxf, pk_exf, dtf);
  pack_gate_k<<<512, 256, 0, stream>>>(eWhf, pk_ehf, dtf);
  pack_gate_k<<<512, 256, 0, stream>>>(eWxb, pk_exb, dtf);
  pack_gate_k<<<512, 256, 0, stream>>>(eWhb, pk_ehb, dtf);
  pack_gate_k<<<512, 256, 0, stream>>>(dWx, pk_dx, dtf);
  pack_gate_k<<<512, 256, 0, stream>>>(dWh, pk_dh, dtf);
  pack_wm_k<<<256, 256, 0, stream>>>(wm, pk_wm, dtf);
  pack_wqt_k<<<512, 256, 0, stream>>>(wq, wqt, dtf);
  pack_w1t_k<<<1024, 256, 0, stream>>>(W1, W1t, dtf);
  pack_bf16_k<<<2, 256, 0, stream>>>(b1, b1p, HID, dtf);
  pack_w2t_k<<<512, 256, 0, stream>>>(W2, W2t, dtf);
  init_states_k<<<64, 256, 0, stream>>>(initH, initC, hIF, hIB, cF, cB, bar, dtf);

  enc_all_k<<<64, 256, 0, stream>>>(article, outF, outB, hIF, hIB, cF, cB,
                                    pk_exf, pk_ehf, pk_exb, pk_ehb, ebf, ebb,
                                    bar, dtf);

  attn_mm_k<<<4096, 256, 0, stream>>>(outF, outB, pk_wm, att);
  seqmean_k<<<32, 256, 0, stream>>>(att, art_lens, sm);
  mv_bb_k<<<64, 256, 0, stream>>>(outF + (size_t)(TS - 1) * BATCH * HID, outB, dhW, hd0, dtf);
  mv_ff_k<<<64, 256, 0, stream>>>(cF, cB, dcW, cdec, dtf);
  proj1_k<<<64, 256, 0, stream>>>(hd0, sm, W1, b1, zbuf, dtf);
  proj2_init_k<<<32, 256, 0, stream>>>(zbuf, W2, emb, xdec, dtf);

  dec_all_k<<<32, 256, 0, stream>>>(xdec, hd0, hd1, cdec, pk_dx, pk_dh, db,
                                    att, wqt, W1t, b1p, W2t, emb, art_lens,
                                    d_out, bar + 64 * FLAG_STRIDE, dtf);
}

// Round 10
// 12943.074 us; speedup vs baseline: 3.6717x; 1.2100x over previous
//
#include <hip/hip_runtime.h>

// Seq2Seq forward. R10: (1) dec_all_k moves to 512 threads/block (8 waves/CU)
// to double memory-level parallelism on the latency-bound Phase-B streams
// (R9: 28 GB/s/CU, concurrency-capped); q/z become one-column-per-thread over
// column-contiguous bf16 packs. (2) article pre-converted to bf16 once
// (buffer aliased onto att) so the encoder stages 32KB not 64KB per step.

#define DI __device__ __forceinline__

constexpr int BATCH = 32;
constexpr int TS = 1024;
constexpr int TG = 64;
constexpr int HID = 512;
constexpr int GD = 2048;
constexpr int EDIM = 256;
constexpr int SPECIAL = 4;
constexpr size_t OFF_H = (size_t)BATCH * TG * EDIM;
constexpr size_t OFF_C = OFF_H + (size_t)BATCH * TG * HID;
constexpr int FLAG_STRIDE = 16;   // dwords (64B) per flag

typedef __attribute__((ext_vector_type(8))) short bf16x8;
typedef __attribute__((ext_vector_type(4))) float f32x4;

DI float b2f(unsigned short u) {
  union { unsigned int i; float f; } v; v.i = ((unsigned int)u) << 16; return v.f;
}
DI unsigned short f2b(float f) {
  union { float f; unsigned int i; } v; v.f = f;
  unsigned int r = v.i + 0x7fffu + ((v.i >> 16) & 1u);
  return (unsigned short)(r >> 16);
}
DI float sigm(float x) { return 1.0f / (1.0f + expf(-x)); }
DI float ldf(const void* p, size_t i, int f32f) {
  return f32f ? ((const float*)p)[i] : b2f(((const unsigned short*)p)[i]);
}
DI void stf(void* p, size_t i, float v, int f32f) {
  if (f32f) ((float*)p)[i] = v; else ((unsigned short*)p)[i] = f2b(v);
}
DI unsigned int ald(const unsigned int* p) {
  return __hip_atomic_load(p, __ATOMIC_RELAXED, __HIP_MEMORY_SCOPE_AGENT);
}
DI void ast(unsigned int* p, unsigned int v) {
  __hip_atomic_store(p, v, __ATOMIC_RELAXED, __HIP_MEMORY_SCOPE_AGENT);
}

__global__ void detect_k(const void* art, int* flag) {
  int tid = threadIdx.x;
  float x = ((const float*)art)[tid + 1024];
  float a = fabsf(x);
  int sane = (x == 0.0f) || (a > 1e-8f && a < 1e4f);
  unsigned long long m = __ballot(sane);
  __shared__ int cnt[4];
  if ((tid & 63) == 0) cnt[tid >> 6] = __popcll(m);
  __syncthreads();
  if (tid == 0) flag[0] = (cnt[0] + cnt[1] + cnt[2] + cnt[3] > 128) ? 1 : 0;
}

__global__ void fill_sig_k(unsigned short* o, int n) {
  int g = blockIdx.x * 256 + threadIdx.x;
  if (g < n) o[g] = 0x42F6;
}

__global__ void pack_gate_k(const void* __restrict__ W,
                            unsigned short* __restrict__ pk, const int* dtf) {
  int f32f = dtf[0];
  int g = blockIdx.x * 256 + threadIdx.x;
  if (g >= (GD * HID) / 8) return;
  int lane = g & 63;
  int kk = (g >> 6) & 15;
  int tile = g >> 10;
  int p = tile * 16 + (lane & 15);
  int nloc = p & 63, blk = p >> 6;
  int orow = (nloc >> 4) * HID + blk * 16 + (nloc & 15);
  int k = kk * 32 + (lane >> 4) * 8;
  unsigned short tmp[8];
#pragma unroll
  for (int j = 0; j < 8; ++j) tmp[j] = f2b(ldf(W, (size_t)orow * HID + k + j, f32f));
  *(uint4*)(pk + (size_t)g * 8) = *(uint4*)tmp;
}

__global__ void pack_wm_k(const void* __restrict__ wm,
                          unsigned short* __restrict__ pk, const int* dtf) {
  int f32f = dtf[0];
  int g = blockIdx.x * 256 + threadIdx.x;
  if (g >= 32 * 32 * 64) return;
  int lane = g & 63;
  int kk = (g >> 6) & 31;
  int nt = g >> 11;
  int col = nt * 16 + (lane & 15);
  int kb = kk * 32 + (lane >> 4) * 8;
  unsigned short tmp[8];
#pragma unroll
  for (int j = 0; j < 8; ++j) tmp[j] = f2b(ldf(wm, (size_t)(kb + j) * HID + col, f32f));
  *(uint4*)(pk + (size_t)g * 8) = *(uint4*)tmp;
}

__global__ void pack_bf16_k(const void* __restrict__ src,
                            unsigned short* __restrict__ dst, int n, const int* dtf) {
  int f32f = dtf[0];
  int g = blockIdx.x * 256 + threadIdx.x;
  if (g < n) dst[g] = f2b(ldf(src, g, f32f));
}

// wq [512k][512n] -> wqc[col c][k] bf16 (thread-contiguous column streams)
__global__ void pack_wqc_k(const void* __restrict__ wq,
                           unsigned short* __restrict__ wqc, const int* dtf) {
  int f32f = dtf[0];
  int g = blockIdx.x * 256 + threadIdx.x;    // 1024 blocks -> 262144
  if (g >= 512 * 512) return;
  int c = g >> 9, k = g & 511;
  wqc[(size_t)c * 512 + k] = f2b(ldf(wq, (size_t)k * HID + c, f32f));
}

// W1 [1024k][512n] -> W1c[col c][k] bf16
__global__ void pack_w1c_k(const void* __restrict__ W1,
                           unsigned short* __restrict__ W1c, const int* dtf) {
  int f32f = dtf[0];
  int g = blockIdx.x * 256 + threadIdx.x;    // 2048 blocks -> 524288
  if (g >= 512 * 1024) return;
  int c = g >> 10, k = g & 1023;
  W1c[(size_t)c * 1024 + k] = f2b(ldf(W1, (size_t)k * HID + c, f32f));
}

// W2 [512k][256n] -> W2t[col c][k] bf16
__global__ void pack_w2t_k(const void* __restrict__ W2,
                           unsigned short* __restrict__ W2t, const int* dtf) {
  int f32f = dtf[0];
  int g = blockIdx.x * 256 + threadIdx.x;    // 512 blocks -> 131072
  if (g >= 256 * 512) return;
  int c = g >> 9, k = g & 511;
  W2t[(size_t)c * 512 + k] = f2b(ldf(W2, (size_t)k * EDIM + c, f32f));
}

// ---------------------------------------------------------------------------
// Persistent bidirectional encoder. Article pre-converted to bf16 (artb).
// ---------------------------------------------------------------------------
__global__ __launch_bounds__(256, 1) void enc_all_k(
    const unsigned short* __restrict__ artb,
    unsigned short* __restrict__ outF, unsigned short* __restrict__ outB,
    const unsigned short* __restrict__ hIF, const unsigned short* __restrict__ hIB,
    float* __restrict__ cF, float* __restrict__ cB,
    const unsigned short* __restrict__ pkXF, const unsigned short* __restrict__ pkHF,
    const unsigned short* __restrict__ pkXB, const unsigned short* __restrict__ pkHB,
    const void* __restrict__ bF, const void* __restrict__ bB,
    int* __restrict__ bar, const int* dtf) {
  const int f32f = dtf[0];
  const int blk = blockIdx.x;
  const int dir = blk >> 5;
  const int blk16 = blk & 31;
  const int tid = threadIdx.x;
  const int lane = tid & 63;
  const int wv = tid >> 6;
  const int tile = blk16 * 4 + wv;

  __shared__ unsigned short lstage[BATCH * HID];
  __shared__ float gbuf[BATCH * 68];

  const unsigned short* pkX = dir ? pkXB : pkXF;
  const unsigned short* pkH = dir ? pkHB : pkHF;
  const void* bias = dir ? bB : bF;
  unsigned short* out = dir ? outB : outF;
  const unsigned short* hI = dir ? hIB : hIF;
  float* cg = dir ? cB : cF;
  int* flp = bar + dir * 32 * FLAG_STRIDE;

  bf16x8 wx[16], wh[16];
  {
    const unsigned short* px = pkX + ((size_t)tile * 16 * 64 + lane) * 8;
    const unsigned short* ph = pkH + ((size_t)tile * 16 * 64 + lane) * 8;
#pragma unroll
    for (int kk = 0; kk < 16; ++kk) {
      wx[kk] = *(const bf16x8*)(px + (size_t)kk * 64 * 8);
      wh[kk] = *(const bf16x8*)(ph + (size_t)kk * 64 * 8);
    }
  }
  const int gb = tid >> 3;
  const int gj = (tid & 7) * 2;
  float c0 = cg[gb * HID + blk16 * 16 + gj];
  float c1 = cg[gb * HID + blk16 * 16 + gj + 1];

  const int r0 = lane & 15;
  const int r1 = 16 + r0;
  const int kbb = (lane >> 4) * 8;
  const int nloc = wv * 16 + (lane & 15);
  const int orow = (nloc >> 4) * HID + blk16 * 16 + (nloc & 15);
  const float bv = ldf(bias, orow, f32f);

  for (int t = 0; t < TS; ++t) {
    const int tsrc = dir ? (TS - 1 - t) : t;
#pragma unroll
    for (int it = 0; it < 8; ++it) {
      int ci = it * 256 + tid;
      int row = ci >> 6;
      int k8 = (ci & 63) << 3;
      unsigned off = (unsigned)(row * 1024 + ((k8 * 2) ^ ((row & 7) << 4)));
      const unsigned short* s = artb + (size_t)tsrc * BATCH * HID +
                                (size_t)row * HID + k8;
      *(uint4*)((char*)lstage + off) = *(const uint4*)s;
    }
    __syncthreads();
    unsigned int* hu = (t == 0)
        ? (unsigned int*)hI
        : (unsigned int*)(out + (size_t)(tsrc + (dir ? 1 : -1)) * BATCH * HID);
    unsigned int hreg[32];
#pragma unroll
    for (int it = 0; it < 32; ++it) hreg[it] = ald(hu + it * 256 + tid);
    f32x4 acc0 = {0.f, 0.f, 0.f, 0.f};
    f32x4 acc1 = {0.f, 0.f, 0.f, 0.f};
#pragma unroll
    for (int kk = 0; kk < 16; ++kk) {
      unsigned o0 = (unsigned)(r0 * 1024 + (((kk * 32 + kbb) * 2) ^ ((r0 & 7) << 4)));
      unsigned o1 = (unsigned)(r1 * 1024 + (((kk * 32 + kbb) * 2) ^ ((r0 & 7) << 4)));
      bf16x8 a0 = *(const bf16x8*)((const char*)lstage + o0);
      bf16x8 a1 = *(const bf16x8*)((const char*)lstage + o1);
      acc0 = __builtin_amdgcn_mfma_f32_16x16x32_bf16(a0, wx[kk], acc0, 0, 0, 0);
      acc1 = __builtin_amdgcn_mfma_f32_16x16x32_bf16(a1, wx[kk], acc1, 0, 0, 0);
    }
    __syncthreads();
#pragma unroll
    for (int it = 0; it < 32; ++it) {
      int dw = it * 256 + tid;
      int row = dw >> 8;
      unsigned lb = (unsigned)(row * 1024 +
                               (((dw & 252) << 2) ^ ((row & 7) << 4)) +
                               ((dw & 3) << 2));
      *(unsigned int*)((char*)lstage + lb) = hreg[it];
    }
    __syncthreads();
#pragma unroll
    for (int kk = 0; kk < 16; ++kk) {
      unsigned o0 = (unsigned)(r0 * 1024 + (((kk * 32 + kbb) * 2) ^ ((r0 & 7) << 4)));
      unsigned o1 = (unsigned)(r1 * 1024 + (((kk * 32 + kbb) * 2) ^ ((r0 & 7) << 4)));
      bf16x8 a0 = *(const bf16x8*)((const char*)lstage + o0);
      bf16x8 a1 = *(const bf16x8*)((const char*)lstage + o1);
      acc0 = __builtin_amdgcn_mfma_f32_16x16x32_bf16(a0, wh[kk], acc0, 0, 0, 0);
      acc1 = __builtin_amdgcn_mfma_f32_16x16x32_bf16(a1, wh[kk], acc1, 0, 0, 0);
    }
#pragma unroll
    for (int r = 0; r < 4; ++r) {
      int brow = (lane >> 4) * 4 + r;
      gbuf[brow * 68 + nloc] = acc0[r] + bv;
      gbuf[(16 + brow) * 68 + nloc] = acc1[r] + bv;
    }
    __syncthreads();
    {
      float gi0 = gbuf[gb * 68 + gj],      gf0 = gbuf[gb * 68 + 16 + gj];
      float gg0 = gbuf[gb * 68 + 32 + gj], go0 = gbuf[gb * 68 + 48 + gj];
      float gi1 = gbuf[gb * 68 + gj + 1],      gf1 = gbuf[gb * 68 + 16 + gj + 1];
      float gg1 = gbuf[gb * 68 + 32 + gj + 1], go1 = gbuf[gb * 68 + 48 + gj + 1];
      float cn0 = sigm(gf0) * c0 + sigm(gi0) * tanhf(gg0); c0 = cn0;
      float cn1 = sigm(gf1) * c1 + sigm(gi1) * tanhf(gg1); c1 = cn1;
      unsigned int hv = (unsigned int)f2b(sigm(go0) * tanhf(cn0)) |
                        ((unsigned int)f2b(sigm(go1) * tanhf(cn1)) << 16);
      ast((unsigned int*)out + (size_t)tsrc * (BATCH * HID / 2) +
              gb * (HID / 2) + blk16 * 8 + (tid & 7), hv);
    }
    if (t + 1 < TS) {
      __syncthreads();
      if (wv == 0) {
        const int target = t + 1;
        if (lane == 0)
          __hip_atomic_store(flp + blk16 * FLAG_STRIDE, target,
                             __ATOMIC_RELAXED, __HIP_MEMORY_SCOPE_AGENT);
        for (;;) {
          int v = (lane < 32)
              ? __hip_atomic_load(flp + lane * FLAG_STRIDE, __ATOMIC_RELAXED,
                                  __HIP_MEMORY_SCOPE_AGENT)
              : 0x7fffffff;
          if (__all(v >= target)) break;
          __builtin_amdgcn_s_sleep(2);
        }
      }
      __syncthreads();
    }
  }
  cg[gb * HID + blk16 * 16 + gj] = c0;
  cg[gb * HID + blk16 * 16 + gj + 1] = c1;
}

// ---------------------------------------------------------------------------
// Persistent fused decoder: 32 blocks x 512 threads (8 waves/CU), 2 grid
// barriers/step. Phase A = LSTM cell on waves 0-3 (tid<256 guards, barriers
// at top level). Phase B = per-batch pipeline over all 8 waves.
// ---------------------------------------------------------------------------
__global__ __launch_bounds__(512, 1) void dec_all_k(
    unsigned short* __restrict__ xdec,
    unsigned short* __restrict__ hd0, unsigned short* __restrict__ hd1,
    const float* __restrict__ cdec,
    const unsigned short* __restrict__ pkX, const unsigned short* __restrict__ pkH,
    const void* __restrict__ dbias,
    const unsigned short* __restrict__ att,
    const unsigned short* __restrict__ wqc,   // [512 col][512 k] bf16
    const unsigned short* __restrict__ W1c,   // [512 col][1024 k] bf16
    const unsigned short* __restrict__ b1p,   // bf16 [512]
    const unsigned short* __restrict__ W2t,   // [256 col][512 k] bf16
    const void* __restrict__ emb, const int* __restrict__ lens,
    void* __restrict__ dout,
    int* __restrict__ flags, const int* dtf) {
  const int f32f = dtf[0];
  const int blk = blockIdx.x;       // 0..31
  const int tid = threadIdx.x;      // 0..511
  const int lane = tid & 63;
  const int wv = tid >> 6;          // 0..7
  __shared__ __align__(16) char smem[49152];

  // Phase-A constants (valid only for tid<256; OOB-indexing loads guarded)
  const int gb = tid >> 3;
  const int gj = (tid & 7) * 2;
  const int r0 = lane & 15;
  const int r1 = 16 + r0;
  const int kbb = (lane >> 4) * 8;
  const int nloc = wv * 16 + (lane & 15);
  float c0 = 0.f, c1 = 0.f, bv = 0.f;
  if (tid < 256) {
    c0 = cdec[gb * HID + blk * 16 + gj];
    c1 = cdec[gb * HID + blk * 16 + gj + 1];
    int orow = (nloc >> 4) * HID + blk * 16 + (nloc & 15);
    bv = ldf(dbias, orow, f32f);
  }

  int ep = 0;
  auto gbar = [&]() {
    __syncthreads();   // vmcnt(0) drain: agent stores globally complete
    ++ep;
    if (wv == 0) {
      if (lane == 0)
        __hip_atomic_store(flags + blk * FLAG_STRIDE, ep, __ATOMIC_RELAXED,
                           __HIP_MEMORY_SCOPE_AGENT);
      for (;;) {
        int v = (lane < 32)
            ? __hip_atomic_load(flags + lane * FLAG_STRIDE, __ATOMIC_RELAXED,
                                __HIP_MEMORY_SCOPE_AGENT)
            : 0x7fffffff;
        if (__all(v >= ep)) break;
        __builtin_amdgcn_s_sleep(2);
      }
    }
    __syncthreads();
  };

  for (int i = 0; i < TG; ++i) {
    unsigned short* hin = (i & 1) ? hd1 : hd0;
    unsigned short* hout = (i & 1) ? hd0 : hd1;

    // ================= Phase A: LSTM cell (waves 0-3) =================
    {
      unsigned short* lstage = (unsigned short*)smem;
      float* gbuf = (float*)(smem + 32768);
      f32x4 acc0 = {0.f, 0.f, 0.f, 0.f};
      f32x4 acc1 = {0.f, 0.f, 0.f, 0.f};
      unsigned int hreg[32];
      if (tid < 256) {
        const unsigned int* xu = (const unsigned int*)xdec;
        unsigned int xreg[32];
#pragma unroll
        for (int it = 0; it < 32; ++it) xreg[it] = ald(xu + it * 256 + tid);
#pragma unroll
        for (int it = 0; it < 32; ++it) {
          int dw = it * 256 + tid;
          int row = dw >> 8;
          unsigned lb = (unsigned)(row * 1024 +
                                   (((dw & 252) << 2) ^ ((row & 7) << 4)) +
                                   ((dw & 3) << 2));
          *(unsigned int*)((char*)lstage + lb) = xreg[it];
        }
      }
      __syncthreads();
      if (tid < 256) {
        const unsigned int* hu = (const unsigned int*)hin;
#pragma unroll
        for (int it = 0; it < 32; ++it) hreg[it] = ald(hu + it * 256 + tid);
        const int tile = blk * 4 + wv;
        const unsigned short* pwx = pkX + (size_t)tile * 16 * 64 * 8;
#pragma unroll
        for (int kk = 0; kk < 16; ++kk) {
          unsigned o0 = (unsigned)(r0 * 1024 + (((kk * 32 + kbb) * 2) ^ ((r0 & 7) << 4)));
          unsigned o1 = (unsigned)(r1 * 1024 + (((kk * 32 + kbb) * 2) ^ ((r0 & 7) << 4)));
          bf16x8 a0 = *(const bf16x8*)((const char*)lstage + o0);
          bf16x8 a1 = *(const bf16x8*)((const char*)lstage + o1);
          bf16x8 bb = *(const bf16x8*)(pwx + (size_t)(kk * 64 + lane) * 8);
          acc0 = __builtin_amdgcn_mfma_f32_16x16x32_bf16(a0, bb, acc0, 0, 0, 0);
          acc1 = __builtin_amdgcn_mfma_f32_16x16x32_bf16(a1, bb, acc1, 0, 0, 0);
        }
      }
      __syncthreads();
      if (tid < 256) {
#pragma unroll
        for (int it = 0; it < 32; ++it) {
          int dw = it * 256 + tid;
          int row = dw >> 8;
          unsigned lb = (unsigned)(row * 1024 +
                                   (((dw & 252) << 2) ^ ((row & 7) << 4)) +
                                   ((dw & 3) << 2));
          *(unsigned int*)((char*)lstage + lb) = hreg[it];
        }
      }
      __syncthreads();
      if (tid < 256) {
        const int tile = blk * 4 + wv;
        const unsigned short* pwh = pkH + (size_t)tile * 16 * 64 * 8;
#pragma unroll
        for (int kk = 0; kk < 16; ++kk) {
          unsigned o0 = (unsigned)(r0 * 1024 + (((kk * 32 + kbb) * 2) ^ ((r0 & 7) << 4)));
          unsigned o1 = (unsigned)(r1 * 1024 + (((kk * 32 + kbb) * 2) ^ ((r0 & 7) << 4)));
          bf16x8 a0 = *(const bf16x8*)((const char*)lstage + o0);
          bf16x8 a1 = *(const bf16x8*)((const char*)lstage + o1);
          bf16x8 bb = *(const bf16x8*)(pwh + (size_t)(kk * 64 + lane) * 8);
          acc0 = __builtin_amdgcn_mfma_f32_16x16x32_bf16(a0, bb, acc0, 0, 0, 0);
          acc1 = __builtin_amdgcn_mfma_f32_16x16x32_bf16(a1, bb, acc1, 0, 0, 0);
        }
#pragma unroll
        for (int r = 0; r < 4; ++r) {
          int brow = (lane >> 4) * 4 + r;
          gbuf[brow * 68 + nloc] = acc0[r] + bv;
          gbuf[(16 + brow) * 68 + nloc] = acc1[r] + bv;
        }
      }
      __syncthreads();
      if (tid < 256) {
        float gi0 = gbuf[gb * 68 + gj],      gf0 = gbuf[gb * 68 + 16 + gj];
        float gg0 = gbuf[gb * 68 + 32 + gj], go0 = gbuf[gb * 68 + 48 + gj];
        float gi1 = gbuf[gb * 68 + gj + 1],      gf1 = gbuf[gb * 68 + 16 + gj + 1];
        float gg1 = gbuf[gb * 68 + 32 + gj + 1], go1 = gbuf[gb * 68 + 48 + gj + 1];
        float cn0 = sigm(gf0) * c0 + sigm(gi0) * tanhf(gg0); c0 = cn0;
        float cn1 = sigm(gf1) * c1 + sigm(gi1) * tanhf(gg1); c1 = cn1;
        float hn0 = sigm(go0) * tanhf(cn0);
        float hn1 = sigm(go1) * tanhf(cn1);
        ast((unsigned int*)hout + gb * (HID / 2) + blk * 8 + (tid & 7),
            (unsigned int)f2b(hn0) | ((unsigned int)f2b(hn1) << 16));
        size_t e0 = ((size_t)gb * TG + i) * HID + blk * 16 + gj;
        stf(dout, OFF_H + e0, hn0, f32f);
        stf(dout, OFF_H + e0 + 1, hn1, f32f);
        stf(dout, OFF_C + e0, cn0, f32f);
        stf(dout, OFF_C + e0 + 1, cn1, f32f);
      }
    }
    gbar();   // h complete

    // ============ Phase B: per-batch pipeline (all 8 waves) ============
    {
      const int b = blk;
      const int len = lens[b];
      unsigned short* lhB = (unsigned short*)smem;            // [512] bf16
      float* qf   = (float*)(smem + 1024);                    // [512] f32
      float* sc   = (float*)(smem + 4096);                    // [1024] f32
      float* red  = (float*)(smem + 8192);                    // [512] f32
      float* cred = (float*)(smem + 12288);                   // [8][512] f32
      float* ctxf = (float*)(smem + 28672);                   // [512] f32
      unsigned short* zl = (unsigned short*)(smem + 30720);   // [512] bf16

      if (tid < 256)
        ((unsigned int*)lhB)[tid] = ald((const unsigned int*)hout + b * 256 + tid);
      __syncthreads();

      // q[tid] = h . wqc[tid]  (one column per thread, contiguous stream)
      {
        const bf16x8* wt = (const bf16x8*)(wqc + (size_t)tid * 512);
        float a = 0.f;
#pragma unroll 8
        for (int k8 = 0; k8 < 64; ++k8) {
          bf16x8 w = wt[k8];
          const unsigned short* hp = lhB + k8 * 8;
#pragma unroll
          for (int e = 0; e < 8; ++e)
            a += b2f(hp[e]) * b2f(((const unsigned short*)&w)[e]);
        }
        qf[tid] = a;
      }
      __syncthreads();

      // score: wave wv rows [wv*128, +128), 4 rows per window
      {
        float qv[8];
#pragma unroll
        for (int j = 0; j < 8; ++j) qv[j] = qf[lane * 8 + j];
        const unsigned short* ab = att + ((size_t)b * TS + wv * 128) * HID + lane * 8;
#pragma unroll 2
        for (int tt = 0; tt < 128; tt += 4) {
          bf16x8 rr0 = *(const bf16x8*)(ab + (size_t)(tt + 0) * HID);
          bf16x8 rr1 = *(const bf16x8*)(ab + (size_t)(tt + 1) * HID);
          bf16x8 rr2 = *(const bf16x8*)(ab + (size_t)(tt + 2) * HID);
          bf16x8 rr3 = *(const bf16x8*)(ab + (size_t)(tt + 3) * HID);
          float s0 = 0.f, s1 = 0.f, s2 = 0.f, s3 = 0.f;
#pragma unroll
          for (int e = 0; e < 8; ++e) {
            s0 += qv[e] * b2f(((const unsigned short*)&rr0)[e]);
            s1 += qv[e] * b2f(((const unsigned short*)&rr1)[e]);
            s2 += qv[e] * b2f(((const unsigned short*)&rr2)[e]);
            s3 += qv[e] * b2f(((const unsigned short*)&rr3)[e]);
          }
          for (int o = 32; o; o >>= 1) {
            s0 += __shfl_xor(s0, o, 64); s1 += __shfl_xor(s1, o, 64);
            s2 += __shfl_xor(s2, o, 64); s3 += __shfl_xor(s3, o, 64);
          }
          if (lane == 0) {
            int t = wv * 128 + tt;
            sc[t] = s0; sc[t + 1] = s1; sc[t + 2] = s2; sc[t + 3] = s3;
          }
        }
      }
      __syncthreads();

      // softmax over sc[0..len) in place (512 threads, 2 elems each)
      {
        float sv[2], mx = -1e30f;
#pragma unroll
        for (int q = 0; q < 2; ++q) {
          int t = q * 512 + tid;
          float v = (t < len) ? sc[t] : -1e30f;
          sv[q] = v; mx = fmaxf(mx, v);
        }
        red[tid] = mx; __syncthreads();
        for (int st = 256; st; st >>= 1) { if (tid < st) red[tid] = fmaxf(red[tid], red[tid + st]); __syncthreads(); }
        mx = red[0]; __syncthreads();
        float e[2], sum = 0.f;
#pragma unroll
        for (int q = 0; q < 2; ++q) { e[q] = (sv[q] > -1e29f) ? expf(sv[q] - mx) : 0.f; sum += e[q]; }
        red[tid] = sum; __syncthreads();
        for (int st = 256; st; st >>= 1) { if (tid < st) red[tid] += red[tid + st]; __syncthreads(); }
        sum = red[0]; __syncthreads();
        sc[tid] = e[0] / sum;
        sc[512 + tid] = e[1] / sum;
      }
      __syncthreads();

      // context: wave wv sums t = wv::8, 4 rows per window
      {
        float ca[8] = {0.f, 0.f, 0.f, 0.f, 0.f, 0.f, 0.f, 0.f};
        const unsigned short* ab = att + (size_t)b * TS * HID + lane * 8;
#pragma unroll 2
        for (int jj = 0; jj < 128; jj += 4) {
          int t0 = wv + 8 * jj;
          bf16x8 rr0 = *(const bf16x8*)(ab + (size_t)(t0)      * HID);
          bf16x8 rr1 = *(const bf16x8*)(ab + (size_t)(t0 + 8)  * HID);
          bf16x8 rr2 = *(const bf16x8*)(ab + (size_t)(t0 + 16) * HID);
          bf16x8 rr3 = *(const bf16x8*)(ab + (size_t)(t0 + 24) * HID);
          float p0 = sc[t0], p1 = sc[t0 + 8], p2 = sc[t0 + 16], p3 = sc[t0 + 24];
#pragma unroll
          for (int e = 0; e < 8; ++e) {
            float v = p0 * b2f(((const unsigned short*)&rr0)[e]);
            v += p1 * b2f(((const unsigned short*)&rr1)[e]);
            v += p2 * b2f(((const unsigned short*)&rr2)[e]);
            v += p3 * b2f(((const unsigned short*)&rr3)[e]);
            ca[e] += v;
          }
        }
#pragma unroll
        for (int e = 0; e < 8; ++e) cred[wv * 512 + lane * 8 + e] = ca[e];
      }
      __syncthreads();
      {
        float s = 0.f;
#pragma unroll
        for (int w = 0; w < 8; ++w) s += cred[w * 512 + tid];
        ctxf[tid] = s;
      }
      __syncthreads();

      // z[tid] = tanh(b1 + h.W1c[tid][0:512] + ctx.W1c[tid][512:1024])
      {
        const bf16x8* wt = (const bf16x8*)(W1c + (size_t)tid * 1024);
        float a = b2f(b1p[tid]);
#pragma unroll 8
        for (int k8 = 0; k8 < 64; ++k8) {
          bf16x8 w = wt[k8];
          const unsigned short* hp = lhB + k8 * 8;
#pragma unroll
          for (int e = 0; e < 8; ++e)
            a += b2f(hp[e]) * b2f(((const unsigned short*)&w)[e]);
        }
#pragma unroll 8
        for (int k8 = 0; k8 < 64; ++k8) {
          bf16x8 w = wt[64 + k8];
          const float* cp = ctxf + k8 * 8;
#pragma unroll
          for (int e = 0; e < 8; ++e)
            a += cp[e] * b2f(((const unsigned short*)&w)[e]);
        }
        zl[tid] = f2b(tanhf(a));
      }
      __syncthreads();

      // out: threads 0..255, col tid
      if (tid < 256) {
        const bf16x8* wt = (const bf16x8*)(W2t + (size_t)tid * 512);
        float a = 0.f;
#pragma unroll 8
        for (int k8 = 0; k8 < 64; ++k8) {
          bf16x8 w = wt[k8];
          const unsigned short* zp = zl + k8 * 8;
#pragma unroll
          for (int e = 0; e < 8; ++e)
            a += b2f(zp[e]) * b2f(((const unsigned short*)&w)[e]);
        }
        stf(dout, ((size_t)b * TG + i) * EDIM + tid, a, f32f);
        unsigned short xb = f2b(a);
        int ob = __shfl_xor((int)xb, 1);
        float ev = ldf(emb, (size_t)(SPECIAL + i + 1) * EDIM + tid, f32f);
        unsigned short eb = f2b(ev);
        int oe = __shfl_xor((int)eb, 1);
        if (!(tid & 1)) {
          unsigned int* xu = (unsigned int*)xdec;
          ast(xu + b * 256 + 128 + (tid >> 1),
              (unsigned int)xb | ((unsigned int)(ob & 0xffff) << 16));
          ast(xu + b * 256 + (tid >> 1),
              (unsigned int)eb | ((unsigned int)(oe & 0xffff) << 16));
        }
      }
    }
    gbar();   // xdec complete
  }
}

__global__ __launch_bounds__(256) void attn_mm_k(
    const unsigned short* __restrict__ outF, const unsigned short* __restrict__ outB,
    const unsigned short* __restrict__ pkwm, unsigned short* __restrict__ att) {
  __shared__ char ldsA[4 * 1040];
  int bid = blockIdx.x;
  int bn = bid & 7, bm = bid >> 3;
  int tid = threadIdx.x, lane = tid & 63, wv = tid >> 6;
  int r0 = bm * 64;
  f32x4 acc[2][2] = {};
  int srow = tid >> 2, skb = tid & 3;
  int mt0 = (wv & 1) * 2, nt0 = (wv >> 1) * 2;
  for (int kk = 0; kk < 32; ++kk) {
    int kg = kk * 32 + skb * 8;
    const unsigned short* src = (kg < HID)
        ? (outF + (size_t)(r0 + srow) * HID + kg)
        : (outB + (size_t)(r0 + srow) * HID + (kg - HID));
    uint4 v = *(const uint4*)src;
    __syncthreads();
    *(uint4*)(ldsA + skb * 1040 + srow * 16) = v;
    __syncthreads();
    bf16x8 a[2], bb[2];
#pragma unroll
    for (int mi = 0; mi < 2; ++mi) {
      int rl = (mt0 + mi) * 16 + (lane & 15);
      a[mi] = *(const bf16x8*)(ldsA + (lane >> 4) * 1040 + rl * 16);
    }
#pragma unroll
    for (int nj = 0; nj < 2; ++nj) {
      int ntg = bn * 4 + nt0 + nj;
      bb[nj] = *(const bf16x8*)(pkwm + ((size_t)(ntg * 32 + kk) * 64 + lane) * 8);
    }
#pragma unroll
    for (int mi = 0; mi < 2; ++mi)
#pragma unroll
      for (int nj = 0; nj < 2; ++nj)
        acc[mi][nj] = __builtin_amdgcn_mfma_f32_16x16x32_bf16(a[mi], bb[nj], acc[mi][nj], 0, 0, 0);
  }
#pragma unroll
  for (int mi = 0; mi < 2; ++mi)
#pragma unroll
    for (int nj = 0; nj < 2; ++nj)
#pragma unroll
      for (int r = 0; r < 4; ++r) {
        int row = r0 + (mt0 + mi) * 16 + (lane >> 4) * 4 + r;
        int t = row >> 5, b = row & 31;
        int h = bn * 64 + (nt0 + nj) * 16 + (lane & 15);
        att[((size_t)b * TS + t) * HID + h] = f2b(acc[mi][nj][r]);
      }
}

__global__ void init_states_k(const void* __restrict__ ih, const void* __restrict__ ic,
                              unsigned short* hIF, unsigned short* hIB,
                              float* cF, float* cB, int* bar, const int* dtf) {
  int f32f = dtf[0];
  int g = blockIdx.x * 256 + threadIdx.x;
  if (g < (64 + 32) * FLAG_STRIDE)
    __hip_atomic_store(bar + g, 0, __ATOMIC_RELAXED, __HIP_MEMORY_SCOPE_AGENT);
  int b = g >> 9, j = g & 511;
  hIF[b * HID + j] = f2b(ldf(ih, j, f32f));
  hIB[b * HID + j] = f2b(ldf(ih, HID + j, f32f));
  cF[b * HID + j] = ldf(ic, j, f32f);
  cB[b * HID + j] = ldf(ic, HID + j, f32f);
}

__global__ void seqmean_k(const unsigned short* __restrict__ att,
                          const int* __restrict__ lens, float* __restrict__ sm) {
  int b = blockIdx.x, tid = threadIdx.x;
  int len = lens[b];
  float a0 = 0.f, a1 = 0.f;
  for (int t = 0; t < len; ++t) {
    const unsigned short* row = att + ((size_t)b * TS + t) * HID;
    a0 += b2f(row[tid]);
    a1 += b2f(row[tid + 256]);
  }
  float fl = (float)len;
  sm[b * HID + tid] = a0 / fl;
  sm[b * HID + tid + 256] = a1 / fl;
}

__global__ void mv_bb_k(const unsigned short* __restrict__ A1,
                        const unsigned short* __restrict__ A2,
                        const void* __restrict__ W, unsigned short* __restrict__ o,
                        const int* dtf) {
  int f32f = dtf[0];
  int g = blockIdx.x * 256 + threadIdx.x;
  int b = g >> 9, n = g & 511;
  float acc = 0.f;
  for (int k = 0; k < HID; ++k) acc += b2f(A1[b * HID + k]) * ldf(W, (size_t)k * HID + n, f32f);
  for (int k = 0; k < HID; ++k) acc += b2f(A2[b * HID + k]) * ldf(W, (size_t)(HID + k) * HID + n, f32f);
  o[b * HID + n] = f2b(acc);
}

__global__ void mv_ff_k(const float* __restrict__ A1, const float* __restrict__ A2,
                        const void* __restrict__ W, float* __restrict__ o, const int* dtf) {
  int f32f = dtf[0];
  int g = blockIdx.x * 256 + threadIdx.x;
  int b = g >> 9, n = g & 511;
  float acc = 0.f;
  for (int k = 0; k < HID; ++k) acc += A1[b * HID + k] * ldf(W, (size_t)k * HID + n, f32f);
  for (int k = 0; k < HID; ++k) acc += A2[b * HID + k] * ldf(W, (size_t)(HID + k) * HID + n, f32f);
  o[b * HID + n] = acc;
}

__global__ void proj1_k(const unsigned short* __restrict__ A1, const float* __restrict__ A2,
                        const void* __restrict__ W1p, const void* __restrict__ b1p,
                        unsigned short* __restrict__ z, const int* dtf) {
  int f32f = dtf[0];
  int g = blockIdx.x * 256 + threadIdx.x;
  int b = g >> 9, n = g & 511;
  float acc = ldf(b1p, n, f32f);
  for (int k = 0; k < HID; ++k) acc += b2f(A1[b * HID + k]) * ldf(W1p, (size_t)k * HID + n, f32f);
  for (int k = 0; k < HID; ++k) acc += A2[b * HID + k] * ldf(W1p, (size_t)(HID + k) * HID + n, f32f);
  z[b * HID + n] = f2b(tanhf(acc));
}

__global__ void proj2_init_k(const unsigned short* __restrict__ z,
                             const void* __restrict__ W2, const void* __restrict__ emb,
                             unsigned short* __restrict__ xdec, const int* dtf) {
  int f32f = dtf[0];
  int g = blockIdx.x * 256 + threadIdx.x;
  int b = g >> 8, n = g & 255;
  float acc = 0.f;
  for (int k = 0; k < HID; ++k) acc += b2f(z[b * HID + k]) * ldf(W2, (size_t)k * EDIM + n, f32f);
  xdec[b * HID + EDIM + n] = f2b(acc);
  xdec[b * HID + n] = f2b(ldf(emb, (size_t)SPECIAL * EDIM + n, f32f));
}

extern "C" void kernel_launch(void* const* d_in, const int* in_sizes, int n_in,
                              void* d_out, int out_size, void* d_ws, size_t ws_size,
                              hipStream_t stream) {
  (void)in_sizes; (void)n_in;
  const void* article = d_in[0];
  const int* art_lens = (const int*)d_in[1];
  const void* emb  = d_in[3];
  const void* eWxf = d_in[4]; const void* eWhf = d_in[5]; const void* ebf = d_in[6];
  const void* eWxb = d_in[7]; const void* eWhb = d_in[8]; const void* ebb = d_in[9];
  const void* initH = d_in[10]; const void* initC = d_in[11];
  const void* dhW = d_in[12]; const void* dcW = d_in[13];
  const void* wm = d_in[14]; const void* wq = d_in[15];
  const void* W1 = d_in[16]; const void* b1 = d_in[17]; const void* W2 = d_in[18];
  const void* dWx = d_in[19]; const void* dWh = d_in[20]; const void* db = d_in[21];

  char* ws = (char*)d_ws;
  size_t off = 0;
  auto take = [&](size_t bytes) -> char* {
    char* p = ws + off;
    off = (off + bytes + 255) & ~(size_t)255;
    return p;
  };
  int* dtf = (int*)take(4);
  int* bar = (int*)take((64 + 32) * FLAG_STRIDE * 4);
  unsigned short* pk_exf = (unsigned short*)take((size_t)GD * HID * 2);
  unsigned short* pk_ehf = (unsigned short*)take((size_t)GD * HID * 2);
  unsigned short* pk_exb = (unsigned short*)take((size_t)GD * HID * 2);
  unsigned short* pk_ehb = (unsigned short*)take((size_t)GD * HID * 2);
  unsigned short* pk_dx  = (unsigned short*)take((size_t)GD * HID * 2);
  unsigned short* pk_dh  = (unsigned short*)take((size_t)GD * HID * 2);
  unsigned short* pk_wm  = (unsigned short*)take((size_t)1024 * HID * 2);
  unsigned short* wqc = (unsigned short*)take((size_t)512 * 512 * 2);
  unsigned short* W1c = (unsigned short*)take((size_t)512 * 1024 * 2);
  unsigned short* b1p = (unsigned short*)take((size_t)HID * 2);
  unsigned short* W2t = (unsigned short*)take((size_t)256 * 512 * 2);
  unsigned short* outF = (unsigned short*)take((size_t)TS * BATCH * HID * 2);
  unsigned short* outB = (unsigned short*)take((size_t)TS * BATCH * HID * 2);
  unsigned short* att  = (unsigned short*)take((size_t)BATCH * TS * HID * 2);
  unsigned short* hIF  = (unsigned short*)take((size_t)BATCH * HID * 2);
  unsigned short* hIB  = (unsigned short*)take((size_t)BATCH * HID * 2);
  float* cF = (float*)take((size_t)BATCH * HID * 4);
  float* cB = (float*)take((size_t)BATCH * HID * 4);
  unsigned short* hd0 = (unsigned short*)take((size_t)BATCH * HID * 2);
  unsigned short* hd1 = (unsigned short*)take((size_t)BATCH * HID * 2);
  float* cdec = (float*)take((size_t)BATCH * HID * 4);
  unsigned short* xdec = (unsigned short*)take((size_t)BATCH * HID * 2);
  unsigned short* zbuf = (unsigned short*)take((size_t)BATCH * HID * 2);
  float* sm = (float*)take((size_t)BATCH * HID * 4);

  if (off > ws_size) {
    fill_sig_k<<<(out_size + 255) / 256, 256, 0, stream>>>((unsigned short*)d_out, out_size);
    return;
  }

  // artb aliases att: article-bf16 live only during encoding; attn_mm_k
  // overwrites att afterwards.
  unsigned short* artb = att;

  detect_k<<<1, 256, 0, stream>>>(article, dtf);
  pack_gate_k<<<512, 256, 0, stream>>>(eWxf, pk_exf, dtf);
  pack_gate_k<<<512, 256, 0, stream>>>(eWhf, pk_ehf, dtf);
  pack_gate_k<<<512, 256, 0, stream>>>(eWxb, pk_exb, dtf);
  pack_gate_k<<<512, 256, 0, stream>>>(eWhb, pk_ehb, dtf);
  pack_gate_k<<<512, 256, 0, stream>>>(dWx, pk_dx, dtf);
  pack_gate_k<<<512, 256, 0, stream>>>(dWh, pk_dh, dtf);
  pack_wm_k<<<256, 256, 0, stream>>>(wm, pk_wm, dtf);
  pack_wqc_k<<<1024, 256, 0, stream>>>(wq, wqc, dtf);
  pack_w1c_k<<<2048, 256, 0, stream>>>(W1, W1c, dtf);
  pack_bf16_k<<<2, 256, 0, stream>>>(b1, b1p, HID, dtf);
  pack_w2t_k<<<512, 256, 0, stream>>>(W2, W2t, dtf);
  pack_bf16_k<<<65536, 256, 0, stream>>>(article, artb, TS * BATCH * HID, dtf);
  init_states_k<<<64, 256, 0, stream>>>(initH, initC, hIF, hIB, cF, cB, bar, dtf);

  enc_all_k<<<64, 256, 0, stream>>>(artb, outF, outB, hIF, hIB, cF, cB,
                                    pk_exf, pk_ehf, pk_exb, pk_ehb, ebf, ebb,
                                    bar, dtf);

  attn_mm_k<<<4096, 256, 0, stream>>>(outF, outB, pk_wm, att);
  seqmean_k<<<32, 256, 0, stream>>>(att, art_lens, sm);
  mv_bb_k<<<64, 256, 0, stream>>>(outF + (size_t)(TS - 1) * BATCH * HID, outB, dhW, hd0, dtf);
  mv_ff_k<<<64, 256, 0, stream>>>(cF, cB, dcW, cdec, dtf);
  proj1_k<<<64, 256, 0, stream>>>(hd0, sm, W1, b1, zbuf, dtf);
  proj2_init_k<<<32, 256, 0, stream>>>(zbuf, W2, emb, xdec, dtf);

  dec_all_k<<<32, 512, 0, stream>>>(xdec, hd0, hd1, cdec, pk_dx, pk_dh, db,
                                    att, wqc, W1c, b1p, W2t, emb, art_lens,
                                    d_out, bar + 64 * FLAG_STRIDE, dtf);
}